// Round 5
// baseline (773.063 us; speedup 1.0000x reference)
//
#include <hip/hip_runtime.h>
#include <hip/hip_cooperative_groups.h>
#include <math.h>

namespace cg = cooperative_groups;

#define NFEAT 128
#define HC    256   // HEADS*NHID
#define NCLS  16
#define DT_F  0.01f
#define EPS_F 1e-5f

__device__ __forceinline__ float bf2f(unsigned short u) {
  union { unsigned int u; float f; } v; v.u = ((unsigned int)u) << 16; return v.f;
}
__device__ __forceinline__ unsigned short f2bf(float f) {
  union { float f; unsigned int u; } v; v.f = f;
  unsigned int r = v.u + 0x7fffu + ((v.u >> 16) & 1u);
  return (unsigned short)(r >> 16);
}

struct Params {
  const float *x, *enc_w, *enc_b, *dec_w, *dec_b, *lo_w, *lo_b,
              *dpl_w, *dpl_b, *dpr_w, *dpr_b, *lin_w, *lin_b, *att;
  const int *row, *col;
  float *Y, *Y2, *X;
  unsigned short *ybfA, *ybfB, *xlb;
  float *xr;
  float4 *sw;
  int *srow, *deg, *cur, *offs, *total;
  float *dis;
  float4 *invq;
  float *fb, *Wext, *bb;
  float *out;
  int n, E;
  float c_decay, c_x, c_k;
};

// ============================ THE MEGA KERNEL ============================
// One cooperative kernel, 9 grid.sync()s, replaces 13 dispatches.
__global__ __launch_bounds__(256, 4) void mega(Params P) {
  cg::grid_group grid = cg::this_grid();
  __shared__ float smem[8192];  // 32KB, reused per phase
  const int tid = threadIdx.x, wave = tid >> 6, lane = tid & 63;
  const int NB = gridDim.x;
  const int gtid = blockIdx.x * 256 + tid;
  const int GSZ = NB * 256;
  const int n = P.n, E = P.E;

  // ---- P0: enc (Y=relu(x@enc_w+b), X=Y, ybf=bf16(Y)) + zero deg/total + Wext/bb
  for (int t = tid; t < NFEAT * 64; t += 256) smem[t] = P.enc_w[t];
  __syncthreads();
  for (int i = blockIdx.x * 4 + wave; i < n; i += NB * 4) {
    const float* xrow = P.x + (size_t)i * NFEAT;
    float acc = P.enc_b[lane];
#pragma unroll 8
    for (int k = 0; k < NFEAT; ++k) acc = fmaf(xrow[k], smem[k * 64 + lane], acc);
    acc = fmaxf(acc, 0.f);
    const size_t idx = (size_t)i * 64 + lane;
    P.Y[idx] = acc; P.X[idx] = acc; P.ybfA[idx] = f2bf(acc);
  }
  for (int t = gtid; t < n; t += GSZ) P.deg[t] = 0;
  if (gtid == 0) *P.total = 0;
  for (int f = gtid; f < 260 * 64; f += GSZ) {
    const int b = f >> 6, j = f & 63;
    float acc = 0.f;
    if (b < 256) {
      const int k = b >> 2, h = b & 3;
#pragma unroll 8
      for (int c = 0; c < 64; ++c)
        acc = fmaf(P.lin_w[k * HC + h * 64 + c], P.lo_w[(size_t)(h * 64 + c) * 64 + j], acc);
      P.Wext[b * 64 + j] = acc;
    } else {
      const int h = b - 256;
#pragma unroll 8
      for (int c = 0; c < 64; ++c)
        acc = fmaf(P.lin_b[h * 64 + c], P.lo_w[(size_t)(h * 64 + c) * 64 + j], acc);
      P.bb[h * 64 + j] = acc;
    }
  }
  grid.sync();  // A

  // ---- P1: dual projection (xr fp32, xlb bf16) + deg atomics
  {
    const int half = NB >> 1;
    const bool doR = (int)blockIdx.x < half;
    const int bid = doR ? blockIdx.x : blockIdx.x - half;
    const float* W = doR ? P.dpr_w : P.dpl_w;
    const float* B = doR ? P.dpr_b : P.dpl_b;
    float wreg[64];
#pragma unroll
    for (int k = 0; k < 64; ++k) wreg[k] = W[k * HC + tid];
    const float bias = B[tid];
    for (int i0 = bid * 4; i0 < n; i0 += half * 4) {
      const float* ap = P.Y + (size_t)i0 * 64;
      float a0 = bias, a1 = bias, a2 = bias, a3 = bias;
#pragma unroll
      for (int k = 0; k < 64; ++k) {
        const float w = wreg[k];
        a0 = fmaf(ap[k], w, a0);
        a1 = fmaf(ap[64 + k], w, a1);
        a2 = fmaf(ap[128 + k], w, a2);
        a3 = fmaf(ap[192 + k], w, a3);
      }
      if (doR) {
        if (i0 + 0 < n) P.xr[(size_t)(i0 + 0) * HC + tid] = a0;
        if (i0 + 1 < n) P.xr[(size_t)(i0 + 1) * HC + tid] = a1;
        if (i0 + 2 < n) P.xr[(size_t)(i0 + 2) * HC + tid] = a2;
        if (i0 + 3 < n) P.xr[(size_t)(i0 + 3) * HC + tid] = a3;
      } else {
        if (i0 + 0 < n) P.xlb[(size_t)(i0 + 0) * HC + tid] = f2bf(a0);
        if (i0 + 1 < n) P.xlb[(size_t)(i0 + 1) * HC + tid] = f2bf(a1);
        if (i0 + 2 < n) P.xlb[(size_t)(i0 + 2) * HC + tid] = f2bf(a2);
        if (i0 + 3 < n) P.xlb[(size_t)(i0 + 3) * HC + tid] = f2bf(a3);
      }
    }
  }
  for (int e = gtid; e < E; e += GSZ) atomicAdd(&P.deg[P.col[e]], 1);
  grid.sync();  // B

  // ---- P2: CSR offsets. Per-block chunk (<=64 nodes): wave-scan deg, one
  // global atomicAdd reserves the range. Offsets non-monotone but disjoint;
  // consumers use end = offs[i] + deg[i].
  {
    const int CH = (n + NB - 1) / NB;  // <= 64 for NB >= 256
    const int s0 = blockIdx.x * CH;
    const int e0 = min(s0 + CH, n);
    if (wave == 0 && s0 < n) {
      const int cnt = e0 - s0;
      const int d = (lane < cnt) ? P.deg[s0 + lane] : 0;
      int sc = d;
#pragma unroll
      for (int m = 1; m < 64; m <<= 1) {
        const int t = __shfl_up(sc, m);
        if (lane >= m) sc += t;
      }
      const int tot = __shfl(sc, 63);
      int base = 0;
      if (lane == 0) base = atomicAdd(P.total, tot);
      base = __shfl(base, 0);
      if (lane < cnt) {
        const int o = base + sc - d;
        P.offs[s0 + lane] = o;
        P.cur[s0 + lane] = o;
        P.dis[s0 + lane] = (d > 0) ? rsqrtf((float)d) : 0.f;
      }
    }
  }
  grid.sync();  // C

  // ---- P3: counting-sort src indices into CSR slots
  for (int e = gtid; e < E; e += GSZ) {
    const int pos = atomicAdd(&P.cur[P.col[e]], 1);
    P.srow[pos] = P.row[e];
  }
  grid.sync();  // D

  // ---- P4: score per dst node (one wave): exp(logit)*dis[r] -> sw;
  // invq = dis[d]/ssum per head; fb = lo_b + sum_h wq_h*bb_h.
  {
    const float4 at4 = ((const float4*)P.att)[lane];
    const ushort4* xlb4 = (const ushort4*)P.xlb;
    const float4* xr4 = (const float4*)P.xr;
    for (int d = blockIdx.x * 4 + wave; d < n; d += NB * 4) {
      const int s = P.offs[d];
      const int e = s + P.deg[d];
      if (s >= e) {
        if (lane == 0) P.invq[d] = make_float4(0.f, 0.f, 0.f, 0.f);
        P.fb[(size_t)d * 64 + lane] = P.lo_b[lane];
        continue;
      }
      const float4 r4 = xr4[(size_t)d * 64 + lane];
      const float dd = P.dis[d];
      float ssum = 0.f, wsum = 0.f;
      int p = s;
      for (; p + 1 < e; p += 2) {
        const int r0 = P.srow[p], r1 = P.srow[p + 1];
        const ushort4 u0 = xlb4[(size_t)r0 * 64 + lane];
        const ushort4 u1 = xlb4[(size_t)r1 * 64 + lane];
        const float di0 = P.dis[r0], di1 = P.dis[r1];
        float vx = bf2f(u0.x) + r4.x, vy = bf2f(u0.y) + r4.y;
        float vz = bf2f(u0.z) + r4.z, vw = bf2f(u0.w) + r4.w;
        vx = fmaxf(vx, 0.2f * vx); vy = fmaxf(vy, 0.2f * vy);
        vz = fmaxf(vz, 0.2f * vz); vw = fmaxf(vw, 0.2f * vw);
        float t0 = vx * at4.x;
        t0 = fmaf(vy, at4.y, t0); t0 = fmaf(vz, at4.z, t0); t0 = fmaf(vw, at4.w, t0);
        vx = bf2f(u1.x) + r4.x; vy = bf2f(u1.y) + r4.y;
        vz = bf2f(u1.z) + r4.z; vw = bf2f(u1.w) + r4.w;
        vx = fmaxf(vx, 0.2f * vx); vy = fmaxf(vy, 0.2f * vy);
        vz = fmaxf(vz, 0.2f * vz); vw = fmaxf(vw, 0.2f * vw);
        float t1 = vx * at4.x;
        t1 = fmaf(vy, at4.y, t1); t1 = fmaf(vz, at4.z, t1); t1 = fmaf(vw, at4.w, t1);
#pragma unroll
        for (int m = 1; m < 16; m <<= 1) {
          t0 += __shfl_xor(t0, m);
          t1 += __shfl_xor(t1, m);
        }
        const float a0 = __expf(t0), a1 = __expf(t1);
        ssum += a0 + a1;
        const float sw0 = a0 * di0, sw1 = a1 * di1;
        wsum += sw0 + sw1;
        if ((lane & 15) == 0) {
          ((float*)&P.sw[p])[lane >> 4] = sw0;
          ((float*)&P.sw[p + 1])[lane >> 4] = sw1;
        }
      }
      for (; p < e; ++p) {
        const int r0 = P.srow[p];
        const ushort4 u0 = xlb4[(size_t)r0 * 64 + lane];
        const float di0 = P.dis[r0];
        float vx = bf2f(u0.x) + r4.x, vy = bf2f(u0.y) + r4.y;
        float vz = bf2f(u0.z) + r4.z, vw = bf2f(u0.w) + r4.w;
        vx = fmaxf(vx, 0.2f * vx); vy = fmaxf(vy, 0.2f * vy);
        vz = fmaxf(vz, 0.2f * vz); vw = fmaxf(vw, 0.2f * vw);
        float t0 = vx * at4.x;
        t0 = fmaf(vy, at4.y, t0); t0 = fmaf(vz, at4.z, t0); t0 = fmaf(vw, at4.w, t0);
#pragma unroll
        for (int m = 1; m < 16; m <<= 1) t0 += __shfl_xor(t0, m);
        const float a0 = __expf(t0);
        ssum += a0;
        const float sw0 = a0 * di0;
        wsum += sw0;
        if ((lane & 15) == 0) ((float*)&P.sw[p])[lane >> 4] = sw0;
      }
      const float inv = dd / (ssum > 0.f ? ssum : 1.f);
      const float wqv = wsum * inv;
      if ((lane & 15) == 0) ((float*)&P.invq[d])[lane >> 4] = inv;
      const float w0 = __shfl(wqv, 0), w1 = __shfl(wqv, 16);
      const float w2 = __shfl(wqv, 32), w3 = __shfl(wqv, 48);
      float v = P.lo_b[lane];
      v = fmaf(w0, P.bb[lane], v);
      v = fmaf(w1, P.bb[64 + lane], v);
      v = fmaf(w2, P.bb[128 + lane], v);
      v = fmaf(w3, P.bb[192 + lane], v);
      P.fb[(size_t)d * 64 + lane] = v;
    }
  }

  // ---- layers: GEMM weights live in registers across all 4 layers
  float wreg2[64];
#pragma unroll
  for (int q = 0; q < 64; ++q) wreg2[q] = P.Wext[(wave * 64 + q) * 64 + lane];
  float* aggl = smem;           // [4][256]
  float* partl = smem + 1024;   // [4][4][64]
  const unsigned short* ybf_in = P.ybfA;
  unsigned short* ybf_out = P.ybfB;
  const float* Yin = P.Y;
  float* Yout = P.Y2;
  const int rounds = (n + 3) >> 2;
  for (int l = 0; l < 4; ++l) {
    grid.sync();  // E, F, G, H
    for (int rb = blockIdx.x; rb < rounds; rb += NB) {
      const int i = rb * 4 + wave;  // wave owns node i
      float4 o = make_float4(0.f, 0.f, 0.f, 0.f);
      if (i < n) {
        const int s = P.offs[i];
        const int e = s + P.deg[i];
        float a0 = 0.f, a1 = 0.f, a2 = 0.f, a3 = 0.f;
        int p = s;
        for (; p + 3 < e; p += 4) {
          const int r0 = P.srow[p], r1 = P.srow[p + 1];
          const int r2 = P.srow[p + 2], r3 = P.srow[p + 3];
          const float4 v0 = P.sw[p], v1 = P.sw[p + 1];
          const float4 v2 = P.sw[p + 2], v3 = P.sw[p + 3];
          const float y0 = bf2f(ybf_in[(size_t)r0 * 64 + lane]);
          const float y1 = bf2f(ybf_in[(size_t)r1 * 64 + lane]);
          const float y2 = bf2f(ybf_in[(size_t)r2 * 64 + lane]);
          const float y3 = bf2f(ybf_in[(size_t)r3 * 64 + lane]);
          a0 = fmaf(v0.x, y0, a0); a1 = fmaf(v0.y, y0, a1);
          a2 = fmaf(v0.z, y0, a2); a3 = fmaf(v0.w, y0, a3);
          a0 = fmaf(v1.x, y1, a0); a1 = fmaf(v1.y, y1, a1);
          a2 = fmaf(v1.z, y1, a2); a3 = fmaf(v1.w, y1, a3);
          a0 = fmaf(v2.x, y2, a0); a1 = fmaf(v2.y, y2, a1);
          a2 = fmaf(v2.z, y2, a2); a3 = fmaf(v2.w, y2, a3);
          a0 = fmaf(v3.x, y3, a0); a1 = fmaf(v3.y, y3, a1);
          a2 = fmaf(v3.z, y3, a2); a3 = fmaf(v3.w, y3, a3);
        }
        for (; p < e; ++p) {
          const int r0 = P.srow[p];
          const float4 v0 = P.sw[p];
          const float y0 = bf2f(ybf_in[(size_t)r0 * 64 + lane]);
          a0 = fmaf(v0.x, y0, a0); a1 = fmaf(v0.y, y0, a1);
          a2 = fmaf(v0.z, y0, a2); a3 = fmaf(v0.w, y0, a3);
        }
        const float4 iv = P.invq[i];
        o.x = a0 * iv.x; o.y = a1 * iv.y; o.z = a2 * iv.z; o.w = a3 * iv.w;
      }
      ((float4*)(aggl + wave * 256))[lane] = o;
      __syncthreads();
      // GEMM: wave covers flat rows wave*64..wave*64+63 for all 4 nodes
      float p0 = 0.f, p1 = 0.f, p2 = 0.f, p3 = 0.f;
#pragma unroll
      for (int q4 = 0; q4 < 16; ++q4) {
        const float4 b0 = *(const float4*)(aggl + 0 * 256 + wave * 64 + q4 * 4);
        const float4 b1 = *(const float4*)(aggl + 1 * 256 + wave * 64 + q4 * 4);
        const float4 b2 = *(const float4*)(aggl + 2 * 256 + wave * 64 + q4 * 4);
        const float4 b3 = *(const float4*)(aggl + 3 * 256 + wave * 64 + q4 * 4);
        const float w0 = wreg2[q4 * 4], w1 = wreg2[q4 * 4 + 1];
        const float w2 = wreg2[q4 * 4 + 2], w3 = wreg2[q4 * 4 + 3];
        p0 = fmaf(b0.x, w0, p0); p0 = fmaf(b0.y, w1, p0);
        p0 = fmaf(b0.z, w2, p0); p0 = fmaf(b0.w, w3, p0);
        p1 = fmaf(b1.x, w0, p1); p1 = fmaf(b1.y, w1, p1);
        p1 = fmaf(b1.z, w2, p1); p1 = fmaf(b1.w, w3, p1);
        p2 = fmaf(b2.x, w0, p2); p2 = fmaf(b2.y, w1, p2);
        p2 = fmaf(b2.z, w2, p2); p2 = fmaf(b2.w, w3, p2);
        p3 = fmaf(b3.x, w0, p3); p3 = fmaf(b3.y, w1, p3);
        p3 = fmaf(b3.z, w2, p3); p3 = fmaf(b3.w, w3, p3);
      }
      partl[(wave * 4 + 0) * 64 + lane] = p0;
      partl[(wave * 4 + 1) * 64 + lane] = p1;
      partl[(wave * 4 + 2) * 64 + lane] = p2;
      partl[(wave * 4 + 3) * 64 + lane] = p3;
      __syncthreads();
      if (i < n) {
        const size_t idx = (size_t)i * 64 + lane;
        float outv = P.fb[idx];
        outv += partl[(0 * 4 + wave) * 64 + lane] + partl[(1 * 4 + wave) * 64 + lane] +
                partl[(2 * 4 + wave) * 64 + lane] + partl[(3 * 4 + wave) * 64 + lane];
        const float y = Yin[idx], xv = P.X[idx];
        const float yn = fmaf(P.c_k, outv, fmaf(P.c_x, xv, P.c_decay * y));
        const float xn = fmaf(DT_F, yn, xv);
        float sy = yn * yn, sx = xn * xn;
#pragma unroll
        for (int m = 32; m > 0; m >>= 1) {
          sy += __shfl_xor(sy, m);
          sx += __shfl_xor(sx, m);
        }
        const float ynn = yn * rsqrtf(sy * (1.f / 64.f) + EPS_F);
        Yout[idx] = ynn;
        ybf_out[idx] = f2bf(ynn);
        P.X[idx] = xn * rsqrtf(sx * (1.f / 64.f) + EPS_F);
      }
    }
    const unsigned short* tb = ybf_in; ybf_in = ybf_out; ybf_out = (unsigned short*)tb;
    const float* ty = Yin; Yin = Yout; Yout = (float*)ty;
  }
  grid.sync();  // I

  // ---- dec: out = X @ dec_w + dec_b
  for (int t = tid; t < 64 * NCLS; t += 256) smem[t] = P.dec_w[t];
  __syncthreads();
  {
    const int jr = tid & 15, ir = tid >> 4;
    for (int i0 = blockIdx.x * 16; i0 < n; i0 += NB * 16) {
      const int i = i0 + ir;
      if (i < n) {
        const float* xrow = P.X + (size_t)i * 64;
        float acc = P.dec_b[jr];
#pragma unroll 8
        for (int k = 0; k < 64; ++k) acc = fmaf(xrow[k], smem[k * NCLS + jr], acc);
        P.out[(size_t)i * NCLS + jr] = acc;
      }
    }
  }
}

// ===================== FALLBACK (round-4 multi-kernel path) =====================
__global__ __launch_bounds__(256) void enc_kernel(
    const float* __restrict__ x, const float* __restrict__ w,
    const float* __restrict__ b, float* __restrict__ Y, float* __restrict__ X,
    unsigned short* __restrict__ Ybf, int n) {
  __shared__ float ws[NFEAT * 64];
  for (int t = threadIdx.x; t < NFEAT * 64; t += blockDim.x) ws[t] = w[t];
  __syncthreads();
  const int wave = threadIdx.x >> 6, lane = threadIdx.x & 63;
  for (int i = blockIdx.x * 4 + wave; i < n; i += gridDim.x * 4) {
    const float* xr = x + (size_t)i * NFEAT;
    float acc = b[lane];
#pragma unroll 8
    for (int k = 0; k < NFEAT; ++k) acc = fmaf(xr[k], ws[k * 64 + lane], acc);
    acc = fmaxf(acc, 0.f);
    const size_t idx = (size_t)i * 64 + lane;
    Y[idx] = acc; X[idx] = acc; Ybf[idx] = f2bf(acc);
  }
}

__global__ __launch_bounds__(256) void proj_kernel(
    const float* __restrict__ Y,
    const float* __restrict__ wl, const float* __restrict__ bl,
    const float* __restrict__ wr, const float* __restrict__ br,
    unsigned short* __restrict__ xlb, float* __restrict__ xr, int n) {
  const int half = gridDim.x >> 1;
  const bool doR = (int)blockIdx.x < half;
  const int bid = doR ? blockIdx.x : blockIdx.x - half;
  const float* __restrict__ W = doR ? wr : wl;
  const float* __restrict__ B = doR ? br : bl;
  float wreg[64];
  const int t = threadIdx.x;
#pragma unroll
  for (int k = 0; k < 64; ++k) wreg[k] = W[k * HC + t];
  const float bias = B[t];
  for (int i0 = bid * 4; i0 < n; i0 += half * 4) {
    const float* ap = Y + (size_t)i0 * 64;
    float a0 = bias, a1 = bias, a2 = bias, a3 = bias;
#pragma unroll
    for (int k = 0; k < 64; ++k) {
      const float w = wreg[k];
      a0 = fmaf(ap[k], w, a0);
      a1 = fmaf(ap[64 + k], w, a1);
      a2 = fmaf(ap[128 + k], w, a2);
      a3 = fmaf(ap[192 + k], w, a3);
    }
    if (doR) {
      if (i0 + 0 < n) xr[(size_t)(i0 + 0) * HC + t] = a0;
      if (i0 + 1 < n) xr[(size_t)(i0 + 1) * HC + t] = a1;
      if (i0 + 2 < n) xr[(size_t)(i0 + 2) * HC + t] = a2;
      if (i0 + 3 < n) xr[(size_t)(i0 + 3) * HC + t] = a3;
    } else {
      if (i0 + 0 < n) xlb[(size_t)(i0 + 0) * HC + t] = f2bf(a0);
      if (i0 + 1 < n) xlb[(size_t)(i0 + 1) * HC + t] = f2bf(a1);
      if (i0 + 2 < n) xlb[(size_t)(i0 + 2) * HC + t] = f2bf(a2);
      if (i0 + 3 < n) xlb[(size_t)(i0 + 3) * HC + t] = f2bf(a3);
    }
  }
}

__global__ __launch_bounds__(64) void wext_kernel(
    const float* __restrict__ lin_w, const float* __restrict__ lin_b,
    const float* __restrict__ lo_w, float* __restrict__ Wext, float* __restrict__ bb) {
  const int j = threadIdx.x;
  const int b = blockIdx.x;
  if (b < 256) {
    const int k = b >> 2, h = b & 3;
    float acc = 0.f;
#pragma unroll 8
    for (int c = 0; c < 64; ++c)
      acc = fmaf(lin_w[k * HC + h * 64 + c], lo_w[(size_t)(h * 64 + c) * 64 + j], acc);
    Wext[b * 64 + j] = acc;
  } else {
    const int h = b - 256;
    float acc = 0.f;
#pragma unroll 8
    for (int c = 0; c < 64; ++c)
      acc = fmaf(lin_b[h * 64 + c], lo_w[(size_t)(h * 64 + c) * 64 + j], acc);
    bb[h * 64 + j] = acc;
  }
}

__global__ __launch_bounds__(256) void deg_kernel(const int* __restrict__ col,
                                                  int* __restrict__ deg, int E) {
  int e = blockIdx.x * blockDim.x + threadIdx.x;
  if (e < E) atomicAdd(&deg[col[e]], 1);
}

__global__ __launch_bounds__(256) void scan_kernel(
    const int* __restrict__ deg, int* __restrict__ offsets, int* __restrict__ cursor,
    float* __restrict__ dis, int n) {
  __shared__ int part[256];
  const int t = threadIdx.x;
  const int chunk = (n + 255) / 256;
  const int start = t * chunk;
  const int end = min(start + chunk, n);
  int s = 0;
  for (int i = start; i < end; ++i) s += deg[i];
  part[t] = s;
  __syncthreads();
  for (int off = 1; off < 256; off <<= 1) {
    int v = (t >= off) ? part[t - off] : 0;
    __syncthreads();
    part[t] += v;
    __syncthreads();
  }
  int run = (t == 0) ? 0 : part[t - 1];
  for (int i = start; i < end; ++i) {
    offsets[i] = run;
    cursor[i] = run;
    int d = deg[i];
    dis[i] = (d > 0) ? rsqrtf((float)d) : 0.f;
    run += d;
  }
}

__global__ __launch_bounds__(256) void scatter_kernel(
    const int* __restrict__ row, const int* __restrict__ col,
    int* __restrict__ cursor, int* __restrict__ srow, int E) {
  int e = blockIdx.x * blockDim.x + threadIdx.x;
  if (e >= E) return;
  int pos = atomicAdd(&cursor[col[e]], 1);
  srow[pos] = row[e];
}

__global__ __launch_bounds__(256) void score_kernel(
    const int* __restrict__ offs, const int* __restrict__ deg,
    const int* __restrict__ srow,
    const ushort4* __restrict__ xlb4, const float4* __restrict__ xr4,
    const float* __restrict__ att, const float* __restrict__ dis,
    const float* __restrict__ bb, const float* __restrict__ lo_b,
    float4* __restrict__ sw, float4* __restrict__ invq, float* __restrict__ fb, int n) {
  const int wave = threadIdx.x >> 6, lane = threadIdx.x & 63;
  const int d = blockIdx.x * 4 + wave;
  if (d >= n) return;
  const int s = offs[d], e = s + deg[d];
  if (s >= e) {
    if (lane == 0) invq[d] = make_float4(0.f, 0.f, 0.f, 0.f);
    fb[(size_t)d * 64 + lane] = lo_b[lane];
    return;
  }
  const float4 at4 = ((const float4*)att)[lane];
  const float4 r4 = xr4[(size_t)d * 64 + lane];
  const float dd = dis[d];
  float ssum = 0.f, wsum = 0.f;
  for (int p = s; p < e; ++p) {
    const int r0 = srow[p];
    const ushort4 u0 = xlb4[(size_t)r0 * 64 + lane];
    const float di0 = dis[r0];
    float vx = bf2f(u0.x) + r4.x, vy = bf2f(u0.y) + r4.y;
    float vz = bf2f(u0.z) + r4.z, vw = bf2f(u0.w) + r4.w;
    vx = fmaxf(vx, 0.2f * vx); vy = fmaxf(vy, 0.2f * vy);
    vz = fmaxf(vz, 0.2f * vz); vw = fmaxf(vw, 0.2f * vw);
    float t0 = vx * at4.x;
    t0 = fmaf(vy, at4.y, t0); t0 = fmaf(vz, at4.z, t0); t0 = fmaf(vw, at4.w, t0);
#pragma unroll
    for (int m = 1; m < 16; m <<= 1) t0 += __shfl_xor(t0, m);
    const float a0 = __expf(t0);
    ssum += a0;
    const float s0 = a0 * di0;
    wsum += s0;
    if ((lane & 15) == 0) ((float*)&sw[p])[lane >> 4] = s0;
  }
  const float inv = dd / (ssum > 0.f ? ssum : 1.f);
  const float wqv = wsum * inv;
  if ((lane & 15) == 0) ((float*)&invq[d])[lane >> 4] = inv;
  const float w0 = __shfl(wqv, 0), w1 = __shfl(wqv, 16);
  const float w2 = __shfl(wqv, 32), w3 = __shfl(wqv, 48);
  float v = lo_b[lane];
  v = fmaf(w0, bb[lane], v);
  v = fmaf(w1, bb[64 + lane], v);
  v = fmaf(w2, bb[128 + lane], v);
  v = fmaf(w3, bb[192 + lane], v);
  fb[(size_t)d * 64 + lane] = v;
}

__global__ __launch_bounds__(256) void layer_fused(
    const int* __restrict__ offs, const int* __restrict__ deg,
    const int* __restrict__ srow,
    const float4* __restrict__ sw, const float4* __restrict__ invq,
    const unsigned short* __restrict__ ybf_in, const float* __restrict__ Wext,
    const float* __restrict__ fb, const float* __restrict__ Yin,
    float* __restrict__ Yout, unsigned short* __restrict__ ybf_out,
    float* __restrict__ X, int n, float c_decay, float c_x, float c_k) {
  const int t = threadIdx.x, tr = t >> 6, lane = t & 63;
  float wreg[64];
#pragma unroll
  for (int q = 0; q < 64; ++q) wreg[q] = Wext[(tr * 64 + q) * 64 + lane];
  __shared__ float aggl[4][HC];
  __shared__ float partl[4][4][64];
  const int rounds = (n + 3) >> 2;
  for (int rb = blockIdx.x; rb < rounds; rb += gridDim.x) {
    const int i = rb * 4 + tr;
    float4 o = make_float4(0.f, 0.f, 0.f, 0.f);
    if (i < n) {
      const int s = offs[i], e = s + deg[i];
      float a0 = 0.f, a1 = 0.f, a2 = 0.f, a3 = 0.f;
      for (int p = s; p < e; ++p) {
        const int r0 = srow[p];
        const float4 v0 = sw[p];
        const float y0 = bf2f(ybf_in[(size_t)r0 * 64 + lane]);
        a0 = fmaf(v0.x, y0, a0); a1 = fmaf(v0.y, y0, a1);
        a2 = fmaf(v0.z, y0, a2); a3 = fmaf(v0.w, y0, a3);
      }
      const float4 iv = invq[i];
      o.x = a0 * iv.x; o.y = a1 * iv.y; o.z = a2 * iv.z; o.w = a3 * iv.w;
    }
    ((float4*)aggl[tr])[lane] = o;
    __syncthreads();
    float p0 = 0.f, p1 = 0.f, p2 = 0.f, p3 = 0.f;
#pragma unroll
    for (int q4 = 0; q4 < 16; ++q4) {
      const float4 b0 = *(const float4*)(&aggl[0][tr * 64 + q4 * 4]);
      const float4 b1 = *(const float4*)(&aggl[1][tr * 64 + q4 * 4]);
      const float4 b2 = *(const float4*)(&aggl[2][tr * 64 + q4 * 4]);
      const float4 b3 = *(const float4*)(&aggl[3][tr * 64 + q4 * 4]);
      const float w0 = wreg[q4 * 4], w1 = wreg[q4 * 4 + 1];
      const float w2 = wreg[q4 * 4 + 2], w3 = wreg[q4 * 4 + 3];
      p0 = fmaf(b0.x, w0, p0); p0 = fmaf(b0.y, w1, p0);
      p0 = fmaf(b0.z, w2, p0); p0 = fmaf(b0.w, w3, p0);
      p1 = fmaf(b1.x, w0, p1); p1 = fmaf(b1.y, w1, p1);
      p1 = fmaf(b1.z, w2, p1); p1 = fmaf(b1.w, w3, p1);
      p2 = fmaf(b2.x, w0, p2); p2 = fmaf(b2.y, w1, p2);
      p2 = fmaf(b2.z, w2, p2); p2 = fmaf(b2.w, w3, p2);
      p3 = fmaf(b3.x, w0, p3); p3 = fmaf(b3.y, w1, p3);
      p3 = fmaf(b3.z, w2, p3); p3 = fmaf(b3.w, w3, p3);
    }
    partl[tr][0][lane] = p0;
    partl[tr][1][lane] = p1;
    partl[tr][2][lane] = p2;
    partl[tr][3][lane] = p3;
    __syncthreads();
    if (i < n) {
      const size_t idx = (size_t)i * 64 + lane;
      float outv = fb[idx];
      outv += partl[0][tr][lane] + partl[1][tr][lane] +
              partl[2][tr][lane] + partl[3][tr][lane];
      const float y = Yin[idx], xv = X[idx];
      const float yn = fmaf(c_k, outv, fmaf(c_x, xv, c_decay * y));
      const float xn = fmaf(DT_F, yn, xv);
      float sy = yn * yn, sx = xn * xn;
#pragma unroll
      for (int m = 32; m > 0; m >>= 1) {
        sy += __shfl_xor(sy, m);
        sx += __shfl_xor(sx, m);
      }
      const float ynn = yn * rsqrtf(sy * (1.f / 64.f) + EPS_F);
      Yout[idx] = ynn;
      ybf_out[idx] = f2bf(ynn);
      X[idx] = xn * rsqrtf(sx * (1.f / 64.f) + EPS_F);
    }
  }
}

__global__ __launch_bounds__(256) void dec_kernel(
    const float* __restrict__ X, const float* __restrict__ w,
    const float* __restrict__ b, float* __restrict__ out, int n) {
  __shared__ float ws[64 * NCLS];
  for (int t = threadIdx.x; t < 64 * NCLS; t += blockDim.x) ws[t] = w[t];
  __syncthreads();
  const int t = threadIdx.x;
  const int jr = t & 15, ir = t >> 4;
  for (int i0 = blockIdx.x * 16; i0 < n; i0 += gridDim.x * 16) {
    const int i = i0 + ir;
    if (i < n) {
      const float* xrow = X + (size_t)i * 64;
      float acc = b[jr];
#pragma unroll 8
      for (int k = 0; k < 64; ++k) acc = fmaf(xrow[k], ws[k * NCLS + jr], acc);
      out[(size_t)i * NCLS + jr] = acc;
    }
  }
}

static inline size_t alignup(size_t x) { return (x + 255) & ~(size_t)255; }

extern "C" void kernel_launch(void* const* d_in, const int* in_sizes, int n_in,
                              void* d_out, int out_size, void* d_ws, size_t ws_size,
                              hipStream_t stream) {
  const float* x     = (const float*)d_in[0];
  const float* enc_w = (const float*)d_in[1];
  const float* enc_b = (const float*)d_in[2];
  const float* dec_w = (const float*)d_in[3];
  const float* dec_b = (const float*)d_in[4];
  const float* lo_w  = (const float*)d_in[5];
  const float* lo_b  = (const float*)d_in[6];
  const float* dpl_w = (const float*)d_in[7];
  const float* dpl_b = (const float*)d_in[8];
  const float* dpr_w = (const float*)d_in[9];
  const float* dpr_b = (const float*)d_in[10];
  const float* lin_w = (const float*)d_in[11];
  const float* lin_b = (const float*)d_in[12];
  const float* att   = (const float*)d_in[13];
  const int*   ei    = (const int*)d_in[14];

  const int n = in_sizes[0] / NFEAT;
  const int E = in_sizes[14] / 2;
  const int* row = ei;
  const int* col = ei + E;

  char* p = (char*)d_ws;
  size_t off = 0;
  auto alloc = [&](size_t bytes) { void* r = p + off; off += alignup(bytes); return r; };
  float*          Y    = (float*)alloc((size_t)n * 64 * 4);
  float*          Y2   = (float*)alloc((size_t)n * 64 * 4);
  float*          X    = (float*)alloc((size_t)n * 64 * 4);
  unsigned short* ybfA = (unsigned short*)alloc((size_t)n * 64 * 2);
  unsigned short* ybfB = (unsigned short*)alloc((size_t)n * 64 * 2);
  unsigned short* xlb  = (unsigned short*)alloc((size_t)n * HC * 2);
  float*          xr   = (float*)alloc((size_t)n * HC * 4);
  float4*         sw   = (float4*)alloc((size_t)E * 16);
  int*            srow = (int*)alloc((size_t)E * 4);
  int*            deg  = (int*)alloc((size_t)n * 4);
  int*            offs = (int*)alloc((size_t)(n + 1) * 4);
  int*            cur  = (int*)alloc((size_t)n * 4);
  float*          dis  = (float*)alloc((size_t)n * 4);
  float4*         invq = (float4*)alloc((size_t)n * 16);
  float*          fb   = (float*)alloc((size_t)n * 64 * 4);
  float*          Wext = (float*)alloc((size_t)HC * 64 * 4);
  float*          bb   = (float*)alloc((size_t)HC * 4);
  int*            total= (int*)alloc(256);

  const double sp = log1p(exp(1.0));
  const float c_decay = (float)(1.0 - 2.0 * sp * sp * 0.01);
  const float c_x     = (float)(-(sp * sp) * 0.01);
  const float c_k     = (float)(sp * 0.01);

  // grid size for cooperative co-residency
  int nbpc = 0;
  if (hipOccupancyMaxActiveBlocksPerMultiprocessor(&nbpc, (const void*)mega, 256, 0)
          != hipSuccess)
    nbpc = 0;
  int GRID = (nbpc > 0) ? nbpc * 256 : 512;
  if (GRID > 1024) GRID = 1024;
  if (GRID < 256) GRID = 256;
  GRID &= ~1;

  Params h;
  h.x = x; h.enc_w = enc_w; h.enc_b = enc_b; h.dec_w = dec_w; h.dec_b = dec_b;
  h.lo_w = lo_w; h.lo_b = lo_b; h.dpl_w = dpl_w; h.dpl_b = dpl_b;
  h.dpr_w = dpr_w; h.dpr_b = dpr_b; h.lin_w = lin_w; h.lin_b = lin_b; h.att = att;
  h.row = row; h.col = col;
  h.Y = Y; h.Y2 = Y2; h.X = X; h.ybfA = ybfA; h.ybfB = ybfB; h.xlb = xlb; h.xr = xr;
  h.sw = sw; h.srow = srow; h.deg = deg; h.cur = cur; h.offs = offs; h.total = total;
  h.dis = dis; h.invq = invq; h.fb = fb; h.Wext = Wext; h.bb = bb;
  h.out = (float*)d_out;
  h.n = n; h.E = E;
  h.c_decay = c_decay; h.c_x = c_x; h.c_k = c_k;

  void* kargs[] = { (void*)&h };
  hipError_t err = hipLaunchCooperativeKernel((const void*)mega, dim3(GRID), dim3(256),
                                              kargs, 0, stream);
  if (err == hipSuccess) return;

  // -------- fallback: round-4 multi-kernel path --------
  hipMemsetAsync(deg, 0, (size_t)n * 4, stream);
  enc_kernel<<<512, 256, 0, stream>>>(x, enc_w, enc_b, Y, X, ybfA, n);
  proj_kernel<<<1024, 256, 0, stream>>>(Y, dpl_w, dpl_b, dpr_w, dpr_b, xlb, xr, n);
  wext_kernel<<<260, 64, 0, stream>>>(lin_w, lin_b, lo_w, Wext, bb);
  deg_kernel<<<(E + 255) / 256, 256, 0, stream>>>(col, deg, E);
  scan_kernel<<<1, 256, 0, stream>>>(deg, offs, cur, dis, n);
  scatter_kernel<<<(E + 255) / 256, 256, 0, stream>>>(row, col, cur, srow, E);
  score_kernel<<<(n + 3) / 4, 256, 0, stream>>>(offs, deg, srow, (const ushort4*)xlb,
                                                (const float4*)xr, att, dis, bb, lo_b,
                                                sw, invq, fb, n);
  const float* Yin = Y;
  float* Yout = Y2;
  const unsigned short* ybf_in = ybfA;
  unsigned short* ybf_out = ybfB;
  for (int l = 0; l < 4; ++l) {
    layer_fused<<<1024, 256, 0, stream>>>(offs, deg, srow, sw, invq, ybf_in, Wext, fb,
                                          Yin, Yout, ybf_out, X, n, c_decay, c_x, c_k);
    const float* ty = Yout; Yout = (float*)Yin; Yin = ty;
    const unsigned short* tb = ybf_out; ybf_out = (unsigned short*)ybf_in; ybf_in = tb;
  }
  dec_kernel<<<(n + 15) / 16, 256, 0, stream>>>(X, dec_w, dec_b, (float*)d_out, n);
}

// Round 6
// 318.494 us; speedup vs baseline: 2.4272x; 2.4272x over previous
//
#include <hip/hip_runtime.h>
#include <math.h>

#define NFEAT 128
#define HC    256   // HEADS*NHID
#define NCLS  16
#define DT_F  0.01f
#define EPS_F 1e-5f

__device__ __forceinline__ float bf2f(unsigned short u) {
  union { unsigned int u; float f; } v; v.u = ((unsigned int)u) << 16; return v.f;
}
__device__ __forceinline__ unsigned short f2bf(float f) {
  union { float f; unsigned int u; } v; v.f = f;
  unsigned int r = v.u + 0x7fffu + ((v.u >> 16) & 1u);
  return (unsigned short)(r >> 16);
}

// ---------------- K1: enc + dual-proj + Wext/bb + deg count; tail-block scan.
// Per quad (4 nodes, 1 per wave): enc via LDS weights, stage Y row in LDS,
// then all 256 threads project 4 nodes against reg-held dpl/dpr columns.
__global__ __launch_bounds__(256) void front_kernel(
    const float* __restrict__ x, const float* __restrict__ enc_w,
    const float* __restrict__ enc_b,
    const float* __restrict__ dpl_w, const float* __restrict__ dpl_b,
    const float* __restrict__ dpr_w, const float* __restrict__ dpr_b,
    const float* __restrict__ lin_w, const float* __restrict__ lin_b,
    const float* __restrict__ lo_w, const int* __restrict__ col,
    float* __restrict__ Y, float* __restrict__ X, unsigned short* __restrict__ ybf,
    unsigned short* __restrict__ xlb, float* __restrict__ xr,
    float* __restrict__ Wext, float* __restrict__ bb,
    int* __restrict__ deg, int* __restrict__ done,
    int* __restrict__ offs, int* __restrict__ cur, float* __restrict__ dis,
    int n, int E) {
  __shared__ float ws[NFEAT * 64];  // 32KB enc weights
  __shared__ float alds[4][64];
  __shared__ int ipart[256];
  __shared__ int flag;
  const int tid = threadIdx.x, wave = tid >> 6, lane = tid & 63;
  const int NB = gridDim.x, gtid = blockIdx.x * 256 + tid, GSZ = NB * 256;
  for (int t = tid; t < NFEAT * 64; t += 256) ws[t] = enc_w[t];
  float wl[64], wr[64];
#pragma unroll
  for (int k = 0; k < 64; ++k) { wl[k] = dpl_w[k * HC + tid]; wr[k] = dpr_w[k * HC + tid]; }
  const float bl = dpl_b[tid], br = dpr_b[tid];
  __syncthreads();
  const int quads = (n + 3) >> 2;
  for (int q = blockIdx.x; q < quads; q += NB) {
    const int i = q * 4 + wave;
    float acc = 0.f;
    if (i < n) {
      const float* xrow = x + (size_t)i * NFEAT;
      acc = enc_b[lane];
#pragma unroll 8
      for (int k = 0; k < NFEAT; ++k) acc = fmaf(xrow[k], ws[k * 64 + lane], acc);
      acc = fmaxf(acc, 0.f);
      const size_t idx = (size_t)i * 64 + lane;
      Y[idx] = acc; X[idx] = acc; ybf[idx] = f2bf(acc);
    }
    alds[wave][lane] = (i < n) ? acc : 0.f;
    __syncthreads();
    float l0 = bl, l1 = bl, l2 = bl, l3 = bl;
    float r0 = br, r1 = br, r2 = br, r3 = br;
#pragma unroll
    for (int k = 0; k < 64; ++k) {
      const float y0 = alds[0][k], y1 = alds[1][k], y2 = alds[2][k], y3 = alds[3][k];
      l0 = fmaf(y0, wl[k], l0); l1 = fmaf(y1, wl[k], l1);
      l2 = fmaf(y2, wl[k], l2); l3 = fmaf(y3, wl[k], l3);
      r0 = fmaf(y0, wr[k], r0); r1 = fmaf(y1, wr[k], r1);
      r2 = fmaf(y2, wr[k], r2); r3 = fmaf(y3, wr[k], r3);
    }
    const int i0 = q * 4;
    if (i0 + 0 < n) { xlb[(size_t)(i0 + 0) * HC + tid] = f2bf(l0); xr[(size_t)(i0 + 0) * HC + tid] = r0; }
    if (i0 + 1 < n) { xlb[(size_t)(i0 + 1) * HC + tid] = f2bf(l1); xr[(size_t)(i0 + 1) * HC + tid] = r1; }
    if (i0 + 2 < n) { xlb[(size_t)(i0 + 2) * HC + tid] = f2bf(l2); xr[(size_t)(i0 + 2) * HC + tid] = r2; }
    if (i0 + 3 < n) { xlb[(size_t)(i0 + 3) * HC + tid] = f2bf(l3); xr[(size_t)(i0 + 3) * HC + tid] = r3; }
    __syncthreads();
  }
  // degree count (device-scope atomics)
  for (int e = gtid; e < E; e += GSZ) atomicAdd(&deg[col[e]], 1);
  // Wext[(k*4+h)*64+j], bb[h*64+j]
  for (int f = gtid; f < 260 * 64; f += GSZ) {
    const int b = f >> 6, j = f & 63;
    float a = 0.f;
    if (b < 256) {
      const int k = b >> 2, h = b & 3;
#pragma unroll 8
      for (int c = 0; c < 64; ++c)
        a = fmaf(lin_w[k * HC + h * 64 + c], lo_w[(size_t)(h * 64 + c) * 64 + j], a);
      Wext[b * 64 + j] = a;
    } else {
      const int h = b - 256;
#pragma unroll 8
      for (int c = 0; c < 64; ++c)
        a = fmaf(lin_b[h * 64 + c], lo_w[(size_t)(h * 64 + c) * 64 + j], a);
      bb[h * 64 + j] = a;
    }
  }
  // ---- tail-block baton: last finished block performs the CSR scan.
  __threadfence();
  __syncthreads();
  if (tid == 0) flag = (atomicAdd(done, 1) == NB - 1) ? 1 : 0;
  __syncthreads();
  if (flag) {
    __threadfence();
    const int chunk = (n + 255) / 256;
    const int start = tid * chunk, end = min(start + chunk, n);
    int s = 0;
    for (int ii = start; ii < end; ++ii)
      s += __hip_atomic_load(&deg[ii], __ATOMIC_RELAXED, __HIP_MEMORY_SCOPE_AGENT);
    ipart[tid] = s;
    __syncthreads();
    for (int off = 1; off < 256; off <<= 1) {
      int v = (tid >= off) ? ipart[tid - off] : 0;
      __syncthreads();
      ipart[tid] += v;
      __syncthreads();
    }
    int run = (tid == 0) ? 0 : ipart[tid - 1];
    for (int ii = start; ii < end; ++ii) {
      const int d = __hip_atomic_load(&deg[ii], __ATOMIC_RELAXED, __HIP_MEMORY_SCOPE_AGENT);
      offs[ii] = run; cur[ii] = run;
      dis[ii] = (d > 0) ? rsqrtf((float)d) : 0.f;
      run += d;
    }
  }
}

// ---------------- K2: counting-sort src into CSR order
__global__ __launch_bounds__(256) void scatter_kernel(
    const int* __restrict__ row, const int* __restrict__ col,
    int* __restrict__ cursor, int* __restrict__ srow, int E) {
  int e = blockIdx.x * blockDim.x + threadIdx.x;
  if (e >= E) return;
  int pos = atomicAdd(&cursor[col[e]], 1);
  srow[pos] = row[e];
}

// ---------------- K3: score (sw/invq/fb) fused with layer-1 agg+GEMM+update.
// Aggregation is linear: accumulate unnormalized Σ (a·dis[r])·ybf[r] during the
// score edge walk, scale by inv per head afterwards.
__global__ __launch_bounds__(256) void score_layer1(
    const int* __restrict__ offs, const int* __restrict__ deg,
    const int* __restrict__ srow,
    const unsigned short* __restrict__ xlb, const float* __restrict__ xr,
    const float* __restrict__ att, const float* __restrict__ dis,
    const float* __restrict__ bb, const float* __restrict__ lo_b,
    const float* __restrict__ Wext, const unsigned short* __restrict__ ybf_in,
    const float* __restrict__ Yin, float* __restrict__ Yout,
    unsigned short* __restrict__ ybf_out, float* __restrict__ X,
    float4* __restrict__ sw, float4* __restrict__ invq, float* __restrict__ fb,
    int n, float c_decay, float c_x, float c_k) {
  const int tid = threadIdx.x, wave = tid >> 6, lane = tid & 63;
  float wreg[64];
#pragma unroll
  for (int q = 0; q < 64; ++q) wreg[q] = Wext[(wave * 64 + q) * 64 + lane];
  __shared__ float aggl[4][HC];
  __shared__ float partl[4][4][64];
  const float4 at4 = ((const float4*)att)[lane];
  const ushort4* xlb4 = (const ushort4*)xlb;
  const float4* xr4 = (const float4*)xr;
  const int quads = (n + 3) >> 2;
  for (int qd = blockIdx.x; qd < quads; qd += gridDim.x) {
    const int i = qd * 4 + wave;
    float g0 = 0.f, g1 = 0.f, g2 = 0.f, g3 = 0.f;
    float fbv = 0.f;
    if (i < n) {
      const int s = offs[i], e = s + deg[i];
      if (s >= e) {
        if (lane == 0) invq[i] = make_float4(0.f, 0.f, 0.f, 0.f);
        fbv = lo_b[lane];
        fb[(size_t)i * 64 + lane] = fbv;
      } else {
        const float4 r4 = xr4[(size_t)i * 64 + lane];
        const float dd = dis[i];
        float ssum = 0.f, wsum = 0.f;
        int p = s;
        for (; p + 1 < e; p += 2) {
          const int ra = srow[p], rb2 = srow[p + 1];
          const ushort4 u0 = xlb4[(size_t)ra * 64 + lane];
          const ushort4 u1 = xlb4[(size_t)rb2 * 64 + lane];
          const float dia = dis[ra], dib = dis[rb2];
          const float ya = bf2f(ybf_in[(size_t)ra * 64 + lane]);
          const float yb = bf2f(ybf_in[(size_t)rb2 * 64 + lane]);
          float vx = bf2f(u0.x) + r4.x, vy = bf2f(u0.y) + r4.y;
          float vz = bf2f(u0.z) + r4.z, vw = bf2f(u0.w) + r4.w;
          vx = fmaxf(vx, 0.2f * vx); vy = fmaxf(vy, 0.2f * vy);
          vz = fmaxf(vz, 0.2f * vz); vw = fmaxf(vw, 0.2f * vw);
          float t0 = vx * at4.x;
          t0 = fmaf(vy, at4.y, t0); t0 = fmaf(vz, at4.z, t0); t0 = fmaf(vw, at4.w, t0);
          vx = bf2f(u1.x) + r4.x; vy = bf2f(u1.y) + r4.y;
          vz = bf2f(u1.z) + r4.z; vw = bf2f(u1.w) + r4.w;
          vx = fmaxf(vx, 0.2f * vx); vy = fmaxf(vy, 0.2f * vy);
          vz = fmaxf(vz, 0.2f * vz); vw = fmaxf(vw, 0.2f * vw);
          float t1 = vx * at4.x;
          t1 = fmaf(vy, at4.y, t1); t1 = fmaf(vz, at4.z, t1); t1 = fmaf(vw, at4.w, t1);
#pragma unroll
          for (int m = 1; m < 16; m <<= 1) {
            t0 += __shfl_xor(t0, m);
            t1 += __shfl_xor(t1, m);
          }
          const float a0 = __expf(t0), a1 = __expf(t1);
          ssum += a0 + a1;
          const float sv0 = a0 * dia, sv1 = a1 * dib;
          wsum += sv0 + sv1;
          if ((lane & 15) == 0) {
            ((float*)&sw[p])[lane >> 4] = sv0;
            ((float*)&sw[p + 1])[lane >> 4] = sv1;
          }
          const float sa0 = __shfl(sv0, 0), sa1 = __shfl(sv0, 16);
          const float sa2 = __shfl(sv0, 32), sa3 = __shfl(sv0, 48);
          g0 = fmaf(sa0, ya, g0); g1 = fmaf(sa1, ya, g1);
          g2 = fmaf(sa2, ya, g2); g3 = fmaf(sa3, ya, g3);
          const float sb0 = __shfl(sv1, 0), sb1 = __shfl(sv1, 16);
          const float sb2 = __shfl(sv1, 32), sb3 = __shfl(sv1, 48);
          g0 = fmaf(sb0, yb, g0); g1 = fmaf(sb1, yb, g1);
          g2 = fmaf(sb2, yb, g2); g3 = fmaf(sb3, yb, g3);
        }
        for (; p < e; ++p) {
          const int ra = srow[p];
          const ushort4 u0 = xlb4[(size_t)ra * 64 + lane];
          const float dia = dis[ra];
          const float ya = bf2f(ybf_in[(size_t)ra * 64 + lane]);
          float vx = bf2f(u0.x) + r4.x, vy = bf2f(u0.y) + r4.y;
          float vz = bf2f(u0.z) + r4.z, vw = bf2f(u0.w) + r4.w;
          vx = fmaxf(vx, 0.2f * vx); vy = fmaxf(vy, 0.2f * vy);
          vz = fmaxf(vz, 0.2f * vz); vw = fmaxf(vw, 0.2f * vw);
          float t0 = vx * at4.x;
          t0 = fmaf(vy, at4.y, t0); t0 = fmaf(vz, at4.z, t0); t0 = fmaf(vw, at4.w, t0);
#pragma unroll
          for (int m = 1; m < 16; m <<= 1) t0 += __shfl_xor(t0, m);
          const float a0 = __expf(t0);
          ssum += a0;
          const float sv0 = a0 * dia;
          wsum += sv0;
          if ((lane & 15) == 0) ((float*)&sw[p])[lane >> 4] = sv0;
          const float sa0 = __shfl(sv0, 0), sa1 = __shfl(sv0, 16);
          const float sa2 = __shfl(sv0, 32), sa3 = __shfl(sv0, 48);
          g0 = fmaf(sa0, ya, g0); g1 = fmaf(sa1, ya, g1);
          g2 = fmaf(sa2, ya, g2); g3 = fmaf(sa3, ya, g3);
        }
        const float inv = dd / (ssum > 0.f ? ssum : 1.f);
        if ((lane & 15) == 0) ((float*)&invq[i])[lane >> 4] = inv;
        const float i0h = __shfl(inv, 0), i1h = __shfl(inv, 16);
        const float i2h = __shfl(inv, 32), i3h = __shfl(inv, 48);
        g0 *= i0h; g1 *= i1h; g2 *= i2h; g3 *= i3h;
        const float wqv = wsum * inv;
        const float w0 = __shfl(wqv, 0), w1 = __shfl(wqv, 16);
        const float w2 = __shfl(wqv, 32), w3 = __shfl(wqv, 48);
        fbv = lo_b[lane];
        fbv = fmaf(w0, bb[lane], fbv);
        fbv = fmaf(w1, bb[64 + lane], fbv);
        fbv = fmaf(w2, bb[128 + lane], fbv);
        fbv = fmaf(w3, bb[192 + lane], fbv);
        fb[(size_t)i * 64 + lane] = fbv;
      }
    }
    float4 o; o.x = g0; o.y = g1; o.z = g2; o.w = g3;
    ((float4*)aggl[wave])[lane] = o;
    __syncthreads();
    float p0 = 0.f, p1 = 0.f, p2 = 0.f, p3 = 0.f;
#pragma unroll
    for (int q4 = 0; q4 < 16; ++q4) {
      const float4 b0 = *(const float4*)(&aggl[0][wave * 64 + q4 * 4]);
      const float4 b1 = *(const float4*)(&aggl[1][wave * 64 + q4 * 4]);
      const float4 b2 = *(const float4*)(&aggl[2][wave * 64 + q4 * 4]);
      const float4 b3 = *(const float4*)(&aggl[3][wave * 64 + q4 * 4]);
      const float w0 = wreg[q4 * 4], w1 = wreg[q4 * 4 + 1];
      const float w2 = wreg[q4 * 4 + 2], w3 = wreg[q4 * 4 + 3];
      p0 = fmaf(b0.x, w0, p0); p0 = fmaf(b0.y, w1, p0);
      p0 = fmaf(b0.z, w2, p0); p0 = fmaf(b0.w, w3, p0);
      p1 = fmaf(b1.x, w0, p1); p1 = fmaf(b1.y, w1, p1);
      p1 = fmaf(b1.z, w2, p1); p1 = fmaf(b1.w, w3, p1);
      p2 = fmaf(b2.x, w0, p2); p2 = fmaf(b2.y, w1, p2);
      p2 = fmaf(b2.z, w2, p2); p2 = fmaf(b2.w, w3, p2);
      p3 = fmaf(b3.x, w0, p3); p3 = fmaf(b3.y, w1, p3);
      p3 = fmaf(b3.z, w2, p3); p3 = fmaf(b3.w, w3, p3);
    }
    partl[wave][0][lane] = p0;
    partl[wave][1][lane] = p1;
    partl[wave][2][lane] = p2;
    partl[wave][3][lane] = p3;
    __syncthreads();
    if (i < n) {
      const size_t idx = (size_t)i * 64 + lane;
      float outv = fbv;
      outv += partl[0][wave][lane] + partl[1][wave][lane] +
              partl[2][wave][lane] + partl[3][wave][lane];
      const float y = Yin[idx], xv = X[idx];
      const float yn = fmaf(c_k, outv, fmaf(c_x, xv, c_decay * y));
      const float xn = fmaf(DT_F, yn, xv);
      float sy = yn * yn, sx = xn * xn;
#pragma unroll
      for (int m = 32; m > 0; m >>= 1) {
        sy += __shfl_xor(sy, m);
        sx += __shfl_xor(sx, m);
      }
      const float ynn = yn * rsqrtf(sy * (1.f / 64.f) + EPS_F);
      Yout[idx] = ynn;
      ybf_out[idx] = f2bf(ynn);
      X[idx] = xn * rsqrtf(sx * (1.f / 64.f) + EPS_F);
    }
    __syncthreads();
  }
}

// ---------------- K4/K5: middle layers (agg -> GEMM -> update)
__global__ __launch_bounds__(256) void layer_fused(
    const int* __restrict__ offs, const int* __restrict__ deg,
    const int* __restrict__ srow,
    const float4* __restrict__ sw, const float4* __restrict__ invq,
    const unsigned short* __restrict__ ybf_in, const float* __restrict__ Wext,
    const float* __restrict__ fb, const float* __restrict__ Yin,
    float* __restrict__ Yout, unsigned short* __restrict__ ybf_out,
    float* __restrict__ X, int n, float c_decay, float c_x, float c_k) {
  const int t = threadIdx.x, tr = t >> 6, lane = t & 63;
  float wreg[64];
#pragma unroll
  for (int q = 0; q < 64; ++q) wreg[q] = Wext[(tr * 64 + q) * 64 + lane];
  __shared__ float aggl[4][HC];
  __shared__ float partl[4][4][64];
  const int rounds = (n + 3) >> 2;
  for (int rb = blockIdx.x; rb < rounds; rb += gridDim.x) {
    const int i = rb * 4 + tr;
    float4 o = make_float4(0.f, 0.f, 0.f, 0.f);
    if (i < n) {
      const int s = offs[i], e = s + deg[i];
      float a0 = 0.f, a1 = 0.f, a2 = 0.f, a3 = 0.f;
      int p = s;
      for (; p + 3 < e; p += 4) {
        const int r0 = srow[p], r1 = srow[p + 1], r2 = srow[p + 2], r3 = srow[p + 3];
        const float4 v0 = sw[p], v1 = sw[p + 1], v2 = sw[p + 2], v3 = sw[p + 3];
        const float y0 = bf2f(ybf_in[(size_t)r0 * 64 + lane]);
        const float y1 = bf2f(ybf_in[(size_t)r1 * 64 + lane]);
        const float y2 = bf2f(ybf_in[(size_t)r2 * 64 + lane]);
        const float y3 = bf2f(ybf_in[(size_t)r3 * 64 + lane]);
        a0 = fmaf(v0.x, y0, a0); a1 = fmaf(v0.y, y0, a1);
        a2 = fmaf(v0.z, y0, a2); a3 = fmaf(v0.w, y0, a3);
        a0 = fmaf(v1.x, y1, a0); a1 = fmaf(v1.y, y1, a1);
        a2 = fmaf(v1.z, y1, a2); a3 = fmaf(v1.w, y1, a3);
        a0 = fmaf(v2.x, y2, a0); a1 = fmaf(v2.y, y2, a1);
        a2 = fmaf(v2.z, y2, a2); a3 = fmaf(v2.w, y2, a3);
        a0 = fmaf(v3.x, y3, a0); a1 = fmaf(v3.y, y3, a1);
        a2 = fmaf(v3.z, y3, a2); a3 = fmaf(v3.w, y3, a3);
      }
      for (; p < e; ++p) {
        const int r0 = srow[p];
        const float4 v0 = sw[p];
        const float y0 = bf2f(ybf_in[(size_t)r0 * 64 + lane]);
        a0 = fmaf(v0.x, y0, a0); a1 = fmaf(v0.y, y0, a1);
        a2 = fmaf(v0.z, y0, a2); a3 = fmaf(v0.w, y0, a3);
      }
      const float4 iv = invq[i];
      o.x = a0 * iv.x; o.y = a1 * iv.y; o.z = a2 * iv.z; o.w = a3 * iv.w;
    }
    ((float4*)aggl[tr])[lane] = o;
    __syncthreads();
    float p0 = 0.f, p1 = 0.f, p2 = 0.f, p3 = 0.f;
#pragma unroll
    for (int q4 = 0; q4 < 16; ++q4) {
      const float4 b0 = *(const float4*)(&aggl[0][tr * 64 + q4 * 4]);
      const float4 b1 = *(const float4*)(&aggl[1][tr * 64 + q4 * 4]);
      const float4 b2 = *(const float4*)(&aggl[2][tr * 64 + q4 * 4]);
      const float4 b3 = *(const float4*)(&aggl[3][tr * 64 + q4 * 4]);
      const float w0 = wreg[q4 * 4], w1 = wreg[q4 * 4 + 1];
      const float w2 = wreg[q4 * 4 + 2], w3 = wreg[q4 * 4 + 3];
      p0 = fmaf(b0.x, w0, p0); p0 = fmaf(b0.y, w1, p0);
      p0 = fmaf(b0.z, w2, p0); p0 = fmaf(b0.w, w3, p0);
      p1 = fmaf(b1.x, w0, p1); p1 = fmaf(b1.y, w1, p1);
      p1 = fmaf(b1.z, w2, p1); p1 = fmaf(b1.w, w3, p1);
      p2 = fmaf(b2.x, w0, p2); p2 = fmaf(b2.y, w1, p2);
      p2 = fmaf(b2.z, w2, p2); p2 = fmaf(b2.w, w3, p2);
      p3 = fmaf(b3.x, w0, p3); p3 = fmaf(b3.y, w1, p3);
      p3 = fmaf(b3.z, w2, p3); p3 = fmaf(b3.w, w3, p3);
    }
    partl[tr][0][lane] = p0;
    partl[tr][1][lane] = p1;
    partl[tr][2][lane] = p2;
    partl[tr][3][lane] = p3;
    __syncthreads();
    if (i < n) {
      const size_t idx = (size_t)i * 64 + lane;
      float outv = fb[idx];
      outv += partl[0][tr][lane] + partl[1][tr][lane] +
              partl[2][tr][lane] + partl[3][tr][lane];
      const float y = Yin[idx], xv = X[idx];
      const float yn = fmaf(c_k, outv, fmaf(c_x, xv, c_decay * y));
      const float xn = fmaf(DT_F, yn, xv);
      float sy = yn * yn, sx = xn * xn;
#pragma unroll
      for (int m = 32; m > 0; m >>= 1) {
        sy += __shfl_xor(sy, m);
        sx += __shfl_xor(sx, m);
      }
      const float ynn = yn * rsqrtf(sy * (1.f / 64.f) + EPS_F);
      Yout[idx] = ynn;
      ybf_out[idx] = f2bf(ynn);
      X[idx] = xn * rsqrtf(sx * (1.f / 64.f) + EPS_F);
    }
    __syncthreads();
  }
}

// ---------------- K6: last layer + fused decoder (no Yout/ybf/X stores)
__global__ __launch_bounds__(256) void layer_last_dec(
    const int* __restrict__ offs, const int* __restrict__ deg,
    const int* __restrict__ srow,
    const float4* __restrict__ sw, const float4* __restrict__ invq,
    const unsigned short* __restrict__ ybf_in, const float* __restrict__ Wext,
    const float* __restrict__ fb, const float* __restrict__ Yin,
    const float* __restrict__ X,
    const float* __restrict__ dec_w, const float* __restrict__ dec_b,
    float* __restrict__ out, int n, float c_decay, float c_x, float c_k) {
  const int t = threadIdx.x, tr = t >> 6, lane = t & 63;
  float wreg[64];
#pragma unroll
  for (int q = 0; q < 64; ++q) wreg[q] = Wext[(tr * 64 + q) * 64 + lane];
  __shared__ float aggl[4][HC];
  __shared__ float partl[4][4][64];
  const int rounds = (n + 3) >> 2;
  for (int rb = blockIdx.x; rb < rounds; rb += gridDim.x) {
    const int i = rb * 4 + tr;
    float4 o = make_float4(0.f, 0.f, 0.f, 0.f);
    if (i < n) {
      const int s = offs[i], e = s + deg[i];
      float a0 = 0.f, a1 = 0.f, a2 = 0.f, a3 = 0.f;
      int p = s;
      for (; p + 3 < e; p += 4) {
        const int r0 = srow[p], r1 = srow[p + 1], r2 = srow[p + 2], r3 = srow[p + 3];
        const float4 v0 = sw[p], v1 = sw[p + 1], v2 = sw[p + 2], v3 = sw[p + 3];
        const float y0 = bf2f(ybf_in[(size_t)r0 * 64 + lane]);
        const float y1 = bf2f(ybf_in[(size_t)r1 * 64 + lane]);
        const float y2 = bf2f(ybf_in[(size_t)r2 * 64 + lane]);
        const float y3 = bf2f(ybf_in[(size_t)r3 * 64 + lane]);
        a0 = fmaf(v0.x, y0, a0); a1 = fmaf(v0.y, y0, a1);
        a2 = fmaf(v0.z, y0, a2); a3 = fmaf(v0.w, y0, a3);
        a0 = fmaf(v1.x, y1, a0); a1 = fmaf(v1.y, y1, a1);
        a2 = fmaf(v1.z, y1, a2); a3 = fmaf(v1.w, y1, a3);
        a0 = fmaf(v2.x, y2, a0); a1 = fmaf(v2.y, y2, a1);
        a2 = fmaf(v2.z, y2, a2); a3 = fmaf(v2.w, y2, a3);
        a0 = fmaf(v3.x, y3, a0); a1 = fmaf(v3.y, y3, a1);
        a2 = fmaf(v3.z, y3, a2); a3 = fmaf(v3.w, y3, a3);
      }
      for (; p < e; ++p) {
        const int r0 = srow[p];
        const float4 v0 = sw[p];
        const float y0 = bf2f(ybf_in[(size_t)r0 * 64 + lane]);
        a0 = fmaf(v0.x, y0, a0); a1 = fmaf(v0.y, y0, a1);
        a2 = fmaf(v0.z, y0, a2); a3 = fmaf(v0.w, y0, a3);
      }
      const float4 iv = invq[i];
      o.x = a0 * iv.x; o.y = a1 * iv.y; o.z = a2 * iv.z; o.w = a3 * iv.w;
    }
    ((float4*)aggl[tr])[lane] = o;
    __syncthreads();
    float p0 = 0.f, p1 = 0.f, p2 = 0.f, p3 = 0.f;
#pragma unroll
    for (int q4 = 0; q4 < 16; ++q4) {
      const float4 b0 = *(const float4*)(&aggl[0][tr * 64 + q4 * 4]);
      const float4 b1 = *(const float4*)(&aggl[1][tr * 64 + q4 * 4]);
      const float4 b2 = *(const float4*)(&aggl[2][tr * 64 + q4 * 4]);
      const float4 b3 = *(const float4*)(&aggl[3][tr * 64 + q4 * 4]);
      const float w0 = wreg[q4 * 4], w1 = wreg[q4 * 4 + 1];
      const float w2 = wreg[q4 * 4 + 2], w3 = wreg[q4 * 4 + 3];
      p0 = fmaf(b0.x, w0, p0); p0 = fmaf(b0.y, w1, p0);
      p0 = fmaf(b0.z, w2, p0); p0 = fmaf(b0.w, w3, p0);
      p1 = fmaf(b1.x, w0, p1); p1 = fmaf(b1.y, w1, p1);
      p1 = fmaf(b1.z, w2, p1); p1 = fmaf(b1.w, w3, p1);
      p2 = fmaf(b2.x, w0, p2); p2 = fmaf(b2.y, w1, p2);
      p2 = fmaf(b2.z, w2, p2); p2 = fmaf(b2.w, w3, p2);
      p3 = fmaf(b3.x, w0, p3); p3 = fmaf(b3.y, w1, p3);
      p3 = fmaf(b3.z, w2, p3); p3 = fmaf(b3.w, w3, p3);
    }
    partl[tr][0][lane] = p0;
    partl[tr][1][lane] = p1;
    partl[tr][2][lane] = p2;
    partl[tr][3][lane] = p3;
    __syncthreads();
    if (i < n) {
      const size_t idx = (size_t)i * 64 + lane;
      float outv = fb[idx];
      outv += partl[0][tr][lane] + partl[1][tr][lane] +
              partl[2][tr][lane] + partl[3][tr][lane];
      const float y = Yin[idx], xv = X[idx];
      const float yn = fmaf(c_k, outv, fmaf(c_x, xv, c_decay * y));
      const float xn = fmaf(DT_F, yn, xv);
      float sx = xn * xn;
#pragma unroll
      for (int m = 32; m > 0; m >>= 1) sx += __shfl_xor(sx, m);
      const float xnn = xn * rsqrtf(sx * (1.f / 64.f) + EPS_F);
      // fused decoder: stage X row, 16-wide partial dots + xor-reduce
      aggl[tr][lane] = xnn;  // same-wave RAW: compiler inserts lgkmcnt
      const int j = lane & 15, kq = lane >> 4;
      float a = 0.f;
#pragma unroll
      for (int k2 = 0; k2 < 16; ++k2) {
        const int k = kq * 16 + k2;
        a = fmaf(aggl[tr][k], dec_w[k * NCLS + j], a);
      }
      a += __shfl_xor(a, 16);
      a += __shfl_xor(a, 32);
      if (lane < 16) out[(size_t)i * NCLS + lane] = a + dec_b[lane];
    }
    __syncthreads();
  }
}

static inline size_t alignup(size_t x) { return (x + 255) & ~(size_t)255; }

extern "C" void kernel_launch(void* const* d_in, const int* in_sizes, int n_in,
                              void* d_out, int out_size, void* d_ws, size_t ws_size,
                              hipStream_t stream) {
  const float* x     = (const float*)d_in[0];
  const float* enc_w = (const float*)d_in[1];
  const float* enc_b = (const float*)d_in[2];
  const float* dec_w = (const float*)d_in[3];
  const float* dec_b = (const float*)d_in[4];
  const float* lo_w  = (const float*)d_in[5];
  const float* lo_b  = (const float*)d_in[6];
  const float* dpl_w = (const float*)d_in[7];
  const float* dpl_b = (const float*)d_in[8];
  const float* dpr_w = (const float*)d_in[9];
  const float* dpr_b = (const float*)d_in[10];
  const float* lin_w = (const float*)d_in[11];
  const float* lin_b = (const float*)d_in[12];
  const float* att   = (const float*)d_in[13];
  const int*   ei    = (const int*)d_in[14];

  const int n = in_sizes[0] / NFEAT;
  const int E = in_sizes[14] / 2;
  const int* row = ei;
  const int* col = ei + E;

  char* p = (char*)d_ws;
  size_t off = 0;
  auto alloc = [&](size_t bytes) { void* r = p + off; off += alignup(bytes); return r; };
  float*          Y    = (float*)alloc((size_t)n * 64 * 4);
  float*          Y2   = (float*)alloc((size_t)n * 64 * 4);
  float*          X    = (float*)alloc((size_t)n * 64 * 4);
  unsigned short* ybfA = (unsigned short*)alloc((size_t)n * 64 * 2);
  unsigned short* ybfB = (unsigned short*)alloc((size_t)n * 64 * 2);
  unsigned short* xlb  = (unsigned short*)alloc((size_t)n * HC * 2);
  float*          xr   = (float*)alloc((size_t)n * HC * 4);
  float4*         sw   = (float4*)alloc((size_t)E * 16);
  int*            srow = (int*)alloc((size_t)E * 4);
  int*            deg  = (int*)alloc((size_t)(n + 64) * 4);  // +done counter
  int*            done = deg + n;
  int*            offs = (int*)alloc((size_t)(n + 1) * 4);
  int*            cur  = (int*)alloc((size_t)n * 4);
  float*          dis  = (float*)alloc((size_t)n * 4);
  float4*         invq = (float4*)alloc((size_t)n * 16);
  float*          fb   = (float*)alloc((size_t)n * 64 * 4);
  float*          Wext = (float*)alloc((size_t)HC * 64 * 4);
  float*          bb   = (float*)alloc((size_t)HC * 4);

  const double sp = log1p(exp(1.0));  // softplus(1): omega = zeta = Ks
  const float c_decay = (float)(1.0 - 2.0 * sp * sp * 0.01);
  const float c_x     = (float)(-(sp * sp) * 0.01);
  const float c_k     = (float)(sp * 0.01);

  // 1) zero deg + done counter
  hipMemsetAsync(deg, 0, (size_t)(n + 64) * 4, stream);
  // 2) enc + proj + Wext + deg count, tail-block CSR scan
  front_kernel<<<1024, 256, 0, stream>>>(x, enc_w, enc_b, dpl_w, dpl_b, dpr_w, dpr_b,
                                         lin_w, lin_b, lo_w, col, Y, X, ybfA, xlb, xr,
                                         Wext, bb, deg, done, offs, cur, dis, n, E);
  // 3) counting-sort into CSR
  scatter_kernel<<<(E + 255) / 256, 256, 0, stream>>>(row, col, cur, srow, E);
  // 4) score + layer 1
  score_layer1<<<1024, 256, 0, stream>>>(offs, deg, srow, xlb, xr, att, dis, bb, lo_b,
                                         Wext, ybfA, Y, Y2, ybfB, X, sw, invq, fb,
                                         n, c_decay, c_x, c_k);
  // 5-6) layers 2-3
  layer_fused<<<1024, 256, 0, stream>>>(offs, deg, srow, sw, invq, ybfB, Wext, fb,
                                        Y2, Y, ybfA, X, n, c_decay, c_x, c_k);
  layer_fused<<<1024, 256, 0, stream>>>(offs, deg, srow, sw, invq, ybfA, Wext, fb,
                                        Y, Y2, ybfB, X, n, c_decay, c_x, c_k);
  // 7) layer 4 + decoder
  layer_last_dec<<<1024, 256, 0, stream>>>(offs, deg, srow, sw, invq, ybfB, Wext, fb,
                                           Y2, X, dec_w, dec_b, (float*)d_out,
                                           n, c_decay, c_x, c_k);
}

// Round 7
// 252.881 us; speedup vs baseline: 3.0570x; 1.2595x over previous
//
#include <hip/hip_runtime.h>
#include <math.h>

#define NFEAT 128
#define HC    256   // HEADS*NHID
#define NCLS  16
#define DT_F  0.01f
#define EPS_F 1e-5f

__device__ __forceinline__ float bf2f(unsigned short u) {
  union { unsigned int u; float f; } v; v.u = ((unsigned int)u) << 16; return v.f;
}
__device__ __forceinline__ unsigned short f2bf(float f) {
  union { float f; unsigned int u; } v; v.f = f;
  unsigned int r = v.u + 0x7fffu + ((v.u >> 16) & 1u);
  return (unsigned short)(r >> 16);
}

// ---------------- K1: enc + dual-proj + Wext/bb + deg count. NO baton/fence.
__global__ __launch_bounds__(256) void front_kernel(
    const float* __restrict__ x, const float* __restrict__ enc_w,
    const float* __restrict__ enc_b,
    const float* __restrict__ dpl_w, const float* __restrict__ dpl_b,
    const float* __restrict__ dpr_w, const float* __restrict__ dpr_b,
    const float* __restrict__ lin_w, const float* __restrict__ lin_b,
    const float* __restrict__ lo_w, const int* __restrict__ col,
    float* __restrict__ Y, float* __restrict__ X, unsigned short* __restrict__ ybf,
    unsigned short* __restrict__ xlb, float* __restrict__ xr,
    float* __restrict__ Wext, float* __restrict__ bb,
    int* __restrict__ deg, int n, int E) {
  __shared__ float ws[NFEAT * 64];  // 32KB enc weights
  __shared__ float alds[4][64];
  const int tid = threadIdx.x, wave = tid >> 6, lane = tid & 63;
  const int NB = gridDim.x, gtid = blockIdx.x * 256 + tid, GSZ = NB * 256;
  for (int t = tid; t < NFEAT * 64; t += 256) ws[t] = enc_w[t];
  float wl[64], wr[64];
#pragma unroll
  for (int k = 0; k < 64; ++k) { wl[k] = dpl_w[k * HC + tid]; wr[k] = dpr_w[k * HC + tid]; }
  const float bl = dpl_b[tid], br = dpr_b[tid];
  __syncthreads();
  const int quads = (n + 3) >> 2;
  for (int q = blockIdx.x; q < quads; q += NB) {
    const int i = q * 4 + wave;
    float acc = 0.f;
    if (i < n) {
      const float* xrow = x + (size_t)i * NFEAT;
      acc = enc_b[lane];
#pragma unroll 8
      for (int k = 0; k < NFEAT; ++k) acc = fmaf(xrow[k], ws[k * 64 + lane], acc);
      acc = fmaxf(acc, 0.f);
      const size_t idx = (size_t)i * 64 + lane;
      Y[idx] = acc; X[idx] = acc; ybf[idx] = f2bf(acc);
    }
    alds[wave][lane] = (i < n) ? acc : 0.f;
    __syncthreads();
    float l0 = bl, l1 = bl, l2 = bl, l3 = bl;
    float r0 = br, r1 = br, r2 = br, r3 = br;
#pragma unroll
    for (int k = 0; k < 64; ++k) {
      const float y0 = alds[0][k], y1 = alds[1][k], y2 = alds[2][k], y3 = alds[3][k];
      l0 = fmaf(y0, wl[k], l0); l1 = fmaf(y1, wl[k], l1);
      l2 = fmaf(y2, wl[k], l2); l3 = fmaf(y3, wl[k], l3);
      r0 = fmaf(y0, wr[k], r0); r1 = fmaf(y1, wr[k], r1);
      r2 = fmaf(y2, wr[k], r2); r3 = fmaf(y3, wr[k], r3);
    }
    const int i0 = q * 4;
    if (i0 + 0 < n) { xlb[(size_t)(i0 + 0) * HC + tid] = f2bf(l0); xr[(size_t)(i0 + 0) * HC + tid] = r0; }
    if (i0 + 1 < n) { xlb[(size_t)(i0 + 1) * HC + tid] = f2bf(l1); xr[(size_t)(i0 + 1) * HC + tid] = r1; }
    if (i0 + 2 < n) { xlb[(size_t)(i0 + 2) * HC + tid] = f2bf(l2); xr[(size_t)(i0 + 2) * HC + tid] = r2; }
    if (i0 + 3 < n) { xlb[(size_t)(i0 + 3) * HC + tid] = f2bf(l3); xr[(size_t)(i0 + 3) * HC + tid] = r3; }
    __syncthreads();
  }
  // degree count (device-scope atomics)
  for (int e = gtid; e < E; e += GSZ) atomicAdd(&deg[col[e]], 1);
  // Wext[(k*4+h)*64+j], bb[h*64+j]
  for (int f = gtid; f < 260 * 64; f += GSZ) {
    const int b = f >> 6, j = f & 63;
    float a = 0.f;
    if (b < 256) {
      const int k = b >> 2, h = b & 3;
#pragma unroll 8
      for (int c = 0; c < 64; ++c)
        a = fmaf(lin_w[k * HC + h * 64 + c], lo_w[(size_t)(h * 64 + c) * 64 + j], a);
      Wext[b * 64 + j] = a;
    } else {
      const int h = b - 256;
#pragma unroll 8
      for (int c = 0; c < 64; ++c)
        a = fmaf(lin_b[h * 64 + c], lo_w[(size_t)(h * 64 + c) * 64 + j], a);
      bb[h * 64 + j] = a;
    }
  }
}

// ---------------- K2: single-block exclusive scan -> offs/cur/dis
__global__ __launch_bounds__(256) void scan_kernel(
    const int* __restrict__ deg, int* __restrict__ offsets, int* __restrict__ cursor,
    float* __restrict__ dis, int n) {
  __shared__ int part[256];
  const int t = threadIdx.x;
  const int chunk = (n + 255) / 256;
  const int start = t * chunk;
  const int end = min(start + chunk, n);
  int s = 0;
  for (int i = start; i < end; ++i) s += deg[i];
  part[t] = s;
  __syncthreads();
  for (int off = 1; off < 256; off <<= 1) {
    int v = (t >= off) ? part[t - off] : 0;
    __syncthreads();
    part[t] += v;
    __syncthreads();
  }
  int run = (t == 0) ? 0 : part[t - 1];
  for (int i = start; i < end; ++i) {
    offsets[i] = run;
    cursor[i] = run;
    const int d = deg[i];
    dis[i] = (d > 0) ? rsqrtf((float)d) : 0.f;
    run += d;
  }
}

// ---------------- K3: counting-sort src into CSR order
__global__ __launch_bounds__(256) void scatter_kernel(
    const int* __restrict__ row, const int* __restrict__ col,
    int* __restrict__ cursor, int* __restrict__ srow, int E) {
  int e = blockIdx.x * blockDim.x + threadIdx.x;
  if (e >= E) return;
  int pos = atomicAdd(&cursor[col[e]], 1);
  srow[pos] = row[e];
}

// ---------------- K4: score (sw/invq/fb) fused with layer-1 agg+GEMM+update.
__global__ __launch_bounds__(256) void score_layer1(
    const int* __restrict__ offs, const int* __restrict__ deg,
    const int* __restrict__ srow,
    const unsigned short* __restrict__ xlb, const float* __restrict__ xr,
    const float* __restrict__ att, const float* __restrict__ dis,
    const float* __restrict__ bb, const float* __restrict__ lo_b,
    const float* __restrict__ Wext, const unsigned short* __restrict__ ybf_in,
    const float* __restrict__ Yin, float* __restrict__ Yout,
    unsigned short* __restrict__ ybf_out, float* __restrict__ X,
    float4* __restrict__ sw, float4* __restrict__ invq, float* __restrict__ fb,
    int n, float c_decay, float c_x, float c_k) {
  const int tid = threadIdx.x, wave = tid >> 6, lane = tid & 63;
  float wreg[64];
#pragma unroll
  for (int q = 0; q < 64; ++q) wreg[q] = Wext[(wave * 64 + q) * 64 + lane];
  __shared__ float aggl[4][HC];
  __shared__ float partl[4][4][64];
  const float4 at4 = ((const float4*)att)[lane];
  const ushort4* xlb4 = (const ushort4*)xlb;
  const float4* xr4 = (const float4*)xr;
  const int quads = (n + 3) >> 2;
  for (int qd = blockIdx.x; qd < quads; qd += gridDim.x) {
    const int i = qd * 4 + wave;
    float g0 = 0.f, g1 = 0.f, g2 = 0.f, g3 = 0.f;
    float fbv = 0.f;
    if (i < n) {
      const int s = offs[i], e = s + deg[i];
      if (s >= e) {
        if (lane == 0) invq[i] = make_float4(0.f, 0.f, 0.f, 0.f);
        fbv = lo_b[lane];
        fb[(size_t)i * 64 + lane] = fbv;
      } else {
        const float4 r4 = xr4[(size_t)i * 64 + lane];
        const float dd = dis[i];
        float ssum = 0.f, wsum = 0.f;
        int p = s;
        for (; p + 1 < e; p += 2) {
          const int ra = srow[p], rb2 = srow[p + 1];
          const ushort4 u0 = xlb4[(size_t)ra * 64 + lane];
          const ushort4 u1 = xlb4[(size_t)rb2 * 64 + lane];
          const float dia = dis[ra], dib = dis[rb2];
          const float ya = bf2f(ybf_in[(size_t)ra * 64 + lane]);
          const float yb = bf2f(ybf_in[(size_t)rb2 * 64 + lane]);
          float vx = bf2f(u0.x) + r4.x, vy = bf2f(u0.y) + r4.y;
          float vz = bf2f(u0.z) + r4.z, vw = bf2f(u0.w) + r4.w;
          vx = fmaxf(vx, 0.2f * vx); vy = fmaxf(vy, 0.2f * vy);
          vz = fmaxf(vz, 0.2f * vz); vw = fmaxf(vw, 0.2f * vw);
          float t0 = vx * at4.x;
          t0 = fmaf(vy, at4.y, t0); t0 = fmaf(vz, at4.z, t0); t0 = fmaf(vw, at4.w, t0);
          vx = bf2f(u1.x) + r4.x; vy = bf2f(u1.y) + r4.y;
          vz = bf2f(u1.z) + r4.z; vw = bf2f(u1.w) + r4.w;
          vx = fmaxf(vx, 0.2f * vx); vy = fmaxf(vy, 0.2f * vy);
          vz = fmaxf(vz, 0.2f * vz); vw = fmaxf(vw, 0.2f * vw);
          float t1 = vx * at4.x;
          t1 = fmaf(vy, at4.y, t1); t1 = fmaf(vz, at4.z, t1); t1 = fmaf(vw, at4.w, t1);
#pragma unroll
          for (int m = 1; m < 16; m <<= 1) {
            t0 += __shfl_xor(t0, m);
            t1 += __shfl_xor(t1, m);
          }
          const float a0 = __expf(t0), a1 = __expf(t1);
          ssum += a0 + a1;
          const float sv0 = a0 * dia, sv1 = a1 * dib;
          wsum += sv0 + sv1;
          if ((lane & 15) == 0) {
            ((float*)&sw[p])[lane >> 4] = sv0;
            ((float*)&sw[p + 1])[lane >> 4] = sv1;
          }
          const float sa0 = __shfl(sv0, 0), sa1 = __shfl(sv0, 16);
          const float sa2 = __shfl(sv0, 32), sa3 = __shfl(sv0, 48);
          g0 = fmaf(sa0, ya, g0); g1 = fmaf(sa1, ya, g1);
          g2 = fmaf(sa2, ya, g2); g3 = fmaf(sa3, ya, g3);
          const float sb0 = __shfl(sv1, 0), sb1 = __shfl(sv1, 16);
          const float sb2 = __shfl(sv1, 32), sb3 = __shfl(sv1, 48);
          g0 = fmaf(sb0, yb, g0); g1 = fmaf(sb1, yb, g1);
          g2 = fmaf(sb2, yb, g2); g3 = fmaf(sb3, yb, g3);
        }
        for (; p < e; ++p) {
          const int ra = srow[p];
          const ushort4 u0 = xlb4[(size_t)ra * 64 + lane];
          const float dia = dis[ra];
          const float ya = bf2f(ybf_in[(size_t)ra * 64 + lane]);
          float vx = bf2f(u0.x) + r4.x, vy = bf2f(u0.y) + r4.y;
          float vz = bf2f(u0.z) + r4.z, vw = bf2f(u0.w) + r4.w;
          vx = fmaxf(vx, 0.2f * vx); vy = fmaxf(vy, 0.2f * vy);
          vz = fmaxf(vz, 0.2f * vz); vw = fmaxf(vw, 0.2f * vw);
          float t0 = vx * at4.x;
          t0 = fmaf(vy, at4.y, t0); t0 = fmaf(vz, at4.z, t0); t0 = fmaf(vw, at4.w, t0);
#pragma unroll
          for (int m = 1; m < 16; m <<= 1) t0 += __shfl_xor(t0, m);
          const float a0 = __expf(t0);
          ssum += a0;
          const float sv0 = a0 * dia;
          wsum += sv0;
          if ((lane & 15) == 0) ((float*)&sw[p])[lane >> 4] = sv0;
          const float sa0 = __shfl(sv0, 0), sa1 = __shfl(sv0, 16);
          const float sa2 = __shfl(sv0, 32), sa3 = __shfl(sv0, 48);
          g0 = fmaf(sa0, ya, g0); g1 = fmaf(sa1, ya, g1);
          g2 = fmaf(sa2, ya, g2); g3 = fmaf(sa3, ya, g3);
        }
        const float inv = dd / (ssum > 0.f ? ssum : 1.f);
        if ((lane & 15) == 0) ((float*)&invq[i])[lane >> 4] = inv;
        const float i0h = __shfl(inv, 0), i1h = __shfl(inv, 16);
        const float i2h = __shfl(inv, 32), i3h = __shfl(inv, 48);
        g0 *= i0h; g1 *= i1h; g2 *= i2h; g3 *= i3h;
        const float wqv = wsum * inv;
        const float w0 = __shfl(wqv, 0), w1 = __shfl(wqv, 16);
        const float w2 = __shfl(wqv, 32), w3 = __shfl(wqv, 48);
        fbv = lo_b[lane];
        fbv = fmaf(w0, bb[lane], fbv);
        fbv = fmaf(w1, bb[64 + lane], fbv);
        fbv = fmaf(w2, bb[128 + lane], fbv);
        fbv = fmaf(w3, bb[192 + lane], fbv);
        fb[(size_t)i * 64 + lane] = fbv;
      }
    }
    float4 o; o.x = g0; o.y = g1; o.z = g2; o.w = g3;
    ((float4*)aggl[wave])[lane] = o;
    __syncthreads();
    float p0 = 0.f, p1 = 0.f, p2 = 0.f, p3 = 0.f;
#pragma unroll
    for (int q4 = 0; q4 < 16; ++q4) {
      const float4 b0 = *(const float4*)(&aggl[0][wave * 64 + q4 * 4]);
      const float4 b1 = *(const float4*)(&aggl[1][wave * 64 + q4 * 4]);
      const float4 b2 = *(const float4*)(&aggl[2][wave * 64 + q4 * 4]);
      const float4 b3 = *(const float4*)(&aggl[3][wave * 64 + q4 * 4]);
      const float w0 = wreg[q4 * 4], w1 = wreg[q4 * 4 + 1];
      const float w2 = wreg[q4 * 4 + 2], w3 = wreg[q4 * 4 + 3];
      p0 = fmaf(b0.x, w0, p0); p0 = fmaf(b0.y, w1, p0);
      p0 = fmaf(b0.z, w2, p0); p0 = fmaf(b0.w, w3, p0);
      p1 = fmaf(b1.x, w0, p1); p1 = fmaf(b1.y, w1, p1);
      p1 = fmaf(b1.z, w2, p1); p1 = fmaf(b1.w, w3, p1);
      p2 = fmaf(b2.x, w0, p2); p2 = fmaf(b2.y, w1, p2);
      p2 = fmaf(b2.z, w2, p2); p2 = fmaf(b2.w, w3, p2);
      p3 = fmaf(b3.x, w0, p3); p3 = fmaf(b3.y, w1, p3);
      p3 = fmaf(b3.z, w2, p3); p3 = fmaf(b3.w, w3, p3);
    }
    partl[wave][0][lane] = p0;
    partl[wave][1][lane] = p1;
    partl[wave][2][lane] = p2;
    partl[wave][3][lane] = p3;
    __syncthreads();
    if (i < n) {
      const size_t idx = (size_t)i * 64 + lane;
      float outv = fbv;
      outv += partl[0][wave][lane] + partl[1][wave][lane] +
              partl[2][wave][lane] + partl[3][wave][lane];
      const float y = Yin[idx], xv = X[idx];
      const float yn = fmaf(c_k, outv, fmaf(c_x, xv, c_decay * y));
      const float xn = fmaf(DT_F, yn, xv);
      float sy = yn * yn, sx = xn * xn;
#pragma unroll
      for (int m = 32; m > 0; m >>= 1) {
        sy += __shfl_xor(sy, m);
        sx += __shfl_xor(sx, m);
      }
      const float ynn = yn * rsqrtf(sy * (1.f / 64.f) + EPS_F);
      Yout[idx] = ynn;
      ybf_out[idx] = f2bf(ynn);
      X[idx] = xn * rsqrtf(sx * (1.f / 64.f) + EPS_F);
    }
    __syncthreads();
  }
}

// ---------------- K5/K6: middle layers (agg -> GEMM -> update)
__global__ __launch_bounds__(256) void layer_fused(
    const int* __restrict__ offs, const int* __restrict__ deg,
    const int* __restrict__ srow,
    const float4* __restrict__ sw, const float4* __restrict__ invq,
    const unsigned short* __restrict__ ybf_in, const float* __restrict__ Wext,
    const float* __restrict__ fb, const float* __restrict__ Yin,
    float* __restrict__ Yout, unsigned short* __restrict__ ybf_out,
    float* __restrict__ X, int n, float c_decay, float c_x, float c_k) {
  const int t = threadIdx.x, tr = t >> 6, lane = t & 63;
  float wreg[64];
#pragma unroll
  for (int q = 0; q < 64; ++q) wreg[q] = Wext[(tr * 64 + q) * 64 + lane];
  __shared__ float aggl[4][HC];
  __shared__ float partl[4][4][64];
  const int rounds = (n + 3) >> 2;
  for (int rb = blockIdx.x; rb < rounds; rb += gridDim.x) {
    const int i = rb * 4 + tr;
    float4 o = make_float4(0.f, 0.f, 0.f, 0.f);
    if (i < n) {
      const int s = offs[i], e = s + deg[i];
      float a0 = 0.f, a1 = 0.f, a2 = 0.f, a3 = 0.f;
      int p = s;
      for (; p + 3 < e; p += 4) {
        const int r0 = srow[p], r1 = srow[p + 1], r2 = srow[p + 2], r3 = srow[p + 3];
        const float4 v0 = sw[p], v1 = sw[p + 1], v2 = sw[p + 2], v3 = sw[p + 3];
        const float y0 = bf2f(ybf_in[(size_t)r0 * 64 + lane]);
        const float y1 = bf2f(ybf_in[(size_t)r1 * 64 + lane]);
        const float y2 = bf2f(ybf_in[(size_t)r2 * 64 + lane]);
        const float y3 = bf2f(ybf_in[(size_t)r3 * 64 + lane]);
        a0 = fmaf(v0.x, y0, a0); a1 = fmaf(v0.y, y0, a1);
        a2 = fmaf(v0.z, y0, a2); a3 = fmaf(v0.w, y0, a3);
        a0 = fmaf(v1.x, y1, a0); a1 = fmaf(v1.y, y1, a1);
        a2 = fmaf(v1.z, y1, a2); a3 = fmaf(v1.w, y1, a3);
        a0 = fmaf(v2.x, y2, a0); a1 = fmaf(v2.y, y2, a1);
        a2 = fmaf(v2.z, y2, a2); a3 = fmaf(v2.w, y2, a3);
        a0 = fmaf(v3.x, y3, a0); a1 = fmaf(v3.y, y3, a1);
        a2 = fmaf(v3.z, y3, a2); a3 = fmaf(v3.w, y3, a3);
      }
      for (; p < e; ++p) {
        const int r0 = srow[p];
        const float4 v0 = sw[p];
        const float y0 = bf2f(ybf_in[(size_t)r0 * 64 + lane]);
        a0 = fmaf(v0.x, y0, a0); a1 = fmaf(v0.y, y0, a1);
        a2 = fmaf(v0.z, y0, a2); a3 = fmaf(v0.w, y0, a3);
      }
      const float4 iv = invq[i];
      o.x = a0 * iv.x; o.y = a1 * iv.y; o.z = a2 * iv.z; o.w = a3 * iv.w;
    }
    ((float4*)aggl[tr])[lane] = o;
    __syncthreads();
    float p0 = 0.f, p1 = 0.f, p2 = 0.f, p3 = 0.f;
#pragma unroll
    for (int q4 = 0; q4 < 16; ++q4) {
      const float4 b0 = *(const float4*)(&aggl[0][tr * 64 + q4 * 4]);
      const float4 b1 = *(const float4*)(&aggl[1][tr * 64 + q4 * 4]);
      const float4 b2 = *(const float4*)(&aggl[2][tr * 64 + q4 * 4]);
      const float4 b3 = *(const float4*)(&aggl[3][tr * 64 + q4 * 4]);
      const float w0 = wreg[q4 * 4], w1 = wreg[q4 * 4 + 1];
      const float w2 = wreg[q4 * 4 + 2], w3 = wreg[q4 * 4 + 3];
      p0 = fmaf(b0.x, w0, p0); p0 = fmaf(b0.y, w1, p0);
      p0 = fmaf(b0.z, w2, p0); p0 = fmaf(b0.w, w3, p0);
      p1 = fmaf(b1.x, w0, p1); p1 = fmaf(b1.y, w1, p1);
      p1 = fmaf(b1.z, w2, p1); p1 = fmaf(b1.w, w3, p1);
      p2 = fmaf(b2.x, w0, p2); p2 = fmaf(b2.y, w1, p2);
      p2 = fmaf(b2.z, w2, p2); p2 = fmaf(b2.w, w3, p2);
      p3 = fmaf(b3.x, w0, p3); p3 = fmaf(b3.y, w1, p3);
      p3 = fmaf(b3.z, w2, p3); p3 = fmaf(b3.w, w3, p3);
    }
    partl[tr][0][lane] = p0;
    partl[tr][1][lane] = p1;
    partl[tr][2][lane] = p2;
    partl[tr][3][lane] = p3;
    __syncthreads();
    if (i < n) {
      const size_t idx = (size_t)i * 64 + lane;
      float outv = fb[idx];
      outv += partl[0][tr][lane] + partl[1][tr][lane] +
              partl[2][tr][lane] + partl[3][tr][lane];
      const float y = Yin[idx], xv = X[idx];
      const float yn = fmaf(c_k, outv, fmaf(c_x, xv, c_decay * y));
      const float xn = fmaf(DT_F, yn, xv);
      float sy = yn * yn, sx = xn * xn;
#pragma unroll
      for (int m = 32; m > 0; m >>= 1) {
        sy += __shfl_xor(sy, m);
        sx += __shfl_xor(sx, m);
      }
      const float ynn = yn * rsqrtf(sy * (1.f / 64.f) + EPS_F);
      Yout[idx] = ynn;
      ybf_out[idx] = f2bf(ynn);
      X[idx] = xn * rsqrtf(sx * (1.f / 64.f) + EPS_F);
    }
    __syncthreads();
  }
}

// ---------------- K7: last layer + fused decoder (no Yout/ybf/X stores)
__global__ __launch_bounds__(256) void layer_last_dec(
    const int* __restrict__ offs, const int* __restrict__ deg,
    const int* __restrict__ srow,
    const float4* __restrict__ sw, const float4* __restrict__ invq,
    const unsigned short* __restrict__ ybf_in, const float* __restrict__ Wext,
    const float* __restrict__ fb, const float* __restrict__ Yin,
    const float* __restrict__ X,
    const float* __restrict__ dec_w, const float* __restrict__ dec_b,
    float* __restrict__ out, int n, float c_decay, float c_x, float c_k) {
  const int t = threadIdx.x, tr = t >> 6, lane = t & 63;
  float wreg[64];
#pragma unroll
  for (int q = 0; q < 64; ++q) wreg[q] = Wext[(tr * 64 + q) * 64 + lane];
  __shared__ float aggl[4][HC];
  __shared__ float partl[4][4][64];
  const int rounds = (n + 3) >> 2;
  for (int rb = blockIdx.x; rb < rounds; rb += gridDim.x) {
    const int i = rb * 4 + tr;
    float4 o = make_float4(0.f, 0.f, 0.f, 0.f);
    if (i < n) {
      const int s = offs[i], e = s + deg[i];
      float a0 = 0.f, a1 = 0.f, a2 = 0.f, a3 = 0.f;
      int p = s;
      for (; p + 3 < e; p += 4) {
        const int r0 = srow[p], r1 = srow[p + 1], r2 = srow[p + 2], r3 = srow[p + 3];
        const float4 v0 = sw[p], v1 = sw[p + 1], v2 = sw[p + 2], v3 = sw[p + 3];
        const float y0 = bf2f(ybf_in[(size_t)r0 * 64 + lane]);
        const float y1 = bf2f(ybf_in[(size_t)r1 * 64 + lane]);
        const float y2 = bf2f(ybf_in[(size_t)r2 * 64 + lane]);
        const float y3 = bf2f(ybf_in[(size_t)r3 * 64 + lane]);
        a0 = fmaf(v0.x, y0, a0); a1 = fmaf(v0.y, y0, a1);
        a2 = fmaf(v0.z, y0, a2); a3 = fmaf(v0.w, y0, a3);
        a0 = fmaf(v1.x, y1, a0); a1 = fmaf(v1.y, y1, a1);
        a2 = fmaf(v1.z, y1, a2); a3 = fmaf(v1.w, y1, a3);
        a0 = fmaf(v2.x, y2, a0); a1 = fmaf(v2.y, y2, a1);
        a2 = fmaf(v2.z, y2, a2); a3 = fmaf(v2.w, y2, a3);
        a0 = fmaf(v3.x, y3, a0); a1 = fmaf(v3.y, y3, a1);
        a2 = fmaf(v3.z, y3, a2); a3 = fmaf(v3.w, y3, a3);
      }
      for (; p < e; ++p) {
        const int r0 = srow[p];
        const float4 v0 = sw[p];
        const float y0 = bf2f(ybf_in[(size_t)r0 * 64 + lane]);
        a0 = fmaf(v0.x, y0, a0); a1 = fmaf(v0.y, y0, a1);
        a2 = fmaf(v0.z, y0, a2); a3 = fmaf(v0.w, y0, a3);
      }
      const float4 iv = invq[i];
      o.x = a0 * iv.x; o.y = a1 * iv.y; o.z = a2 * iv.z; o.w = a3 * iv.w;
    }
    ((float4*)aggl[tr])[lane] = o;
    __syncthreads();
    float p0 = 0.f, p1 = 0.f, p2 = 0.f, p3 = 0.f;
#pragma unroll
    for (int q4 = 0; q4 < 16; ++q4) {
      const float4 b0 = *(const float4*)(&aggl[0][tr * 64 + q4 * 4]);
      const float4 b1 = *(const float4*)(&aggl[1][tr * 64 + q4 * 4]);
      const float4 b2 = *(const float4*)(&aggl[2][tr * 64 + q4 * 4]);
      const float4 b3 = *(const float4*)(&aggl[3][tr * 64 + q4 * 4]);
      const float w0 = wreg[q4 * 4], w1 = wreg[q4 * 4 + 1];
      const float w2 = wreg[q4 * 4 + 2], w3 = wreg[q4 * 4 + 3];
      p0 = fmaf(b0.x, w0, p0); p0 = fmaf(b0.y, w1, p0);
      p0 = fmaf(b0.z, w2, p0); p0 = fmaf(b0.w, w3, p0);
      p1 = fmaf(b1.x, w0, p1); p1 = fmaf(b1.y, w1, p1);
      p1 = fmaf(b1.z, w2, p1); p1 = fmaf(b1.w, w3, p1);
      p2 = fmaf(b2.x, w0, p2); p2 = fmaf(b2.y, w1, p2);
      p2 = fmaf(b2.z, w2, p2); p2 = fmaf(b2.w, w3, p2);
      p3 = fmaf(b3.x, w0, p3); p3 = fmaf(b3.y, w1, p3);
      p3 = fmaf(b3.z, w2, p3); p3 = fmaf(b3.w, w3, p3);
    }
    partl[tr][0][lane] = p0;
    partl[tr][1][lane] = p1;
    partl[tr][2][lane] = p2;
    partl[tr][3][lane] = p3;
    __syncthreads();
    if (i < n) {
      const size_t idx = (size_t)i * 64 + lane;
      float outv = fb[idx];
      outv += partl[0][tr][lane] + partl[1][tr][lane] +
              partl[2][tr][lane] + partl[3][tr][lane];
      const float y = Yin[idx], xv = X[idx];
      const float yn = fmaf(c_k, outv, fmaf(c_x, xv, c_decay * y));
      const float xn = fmaf(DT_F, yn, xv);
      float sx = xn * xn;
#pragma unroll
      for (int m = 32; m > 0; m >>= 1) sx += __shfl_xor(sx, m);
      const float xnn = xn * rsqrtf(sx * (1.f / 64.f) + EPS_F);
      // fused decoder: stage X row, 16-wide partial dots + xor-reduce
      aggl[tr][lane] = xnn;  // same-wave RAW: compiler inserts lgkmcnt
      const int j = lane & 15, kq = lane >> 4;
      float a = 0.f;
#pragma unroll
      for (int k2 = 0; k2 < 16; ++k2) {
        const int k = kq * 16 + k2;
        a = fmaf(aggl[tr][k], dec_w[k * NCLS + j], a);
      }
      a += __shfl_xor(a, 16);
      a += __shfl_xor(a, 32);
      if (lane < 16) out[(size_t)i * NCLS + lane] = a + dec_b[lane];
    }
    __syncthreads();
  }
}

static inline size_t alignup(size_t x) { return (x + 255) & ~(size_t)255; }

extern "C" void kernel_launch(void* const* d_in, const int* in_sizes, int n_in,
                              void* d_out, int out_size, void* d_ws, size_t ws_size,
                              hipStream_t stream) {
  const float* x     = (const float*)d_in[0];
  const float* enc_w = (const float*)d_in[1];
  const float* enc_b = (const float*)d_in[2];
  const float* dec_w = (const float*)d_in[3];
  const float* dec_b = (const float*)d_in[4];
  const float* lo_w  = (const float*)d_in[5];
  const float* lo_b  = (const float*)d_in[6];
  const float* dpl_w = (const float*)d_in[7];
  const float* dpl_b = (const float*)d_in[8];
  const float* dpr_w = (const float*)d_in[9];
  const float* dpr_b = (const float*)d_in[10];
  const float* lin_w = (const float*)d_in[11];
  const float* lin_b = (const float*)d_in[12];
  const float* att   = (const float*)d_in[13];
  const int*   ei    = (const int*)d_in[14];

  const int n = in_sizes[0] / NFEAT;
  const int E = in_sizes[14] / 2;
  const int* row = ei;
  const int* col = ei + E;

  char* p = (char*)d_ws;
  size_t off = 0;
  auto alloc = [&](size_t bytes) { void* r = p + off; off += alignup(bytes); return r; };
  float*          Y    = (float*)alloc((size_t)n * 64 * 4);
  float*          Y2   = (float*)alloc((size_t)n * 64 * 4);
  float*          X    = (float*)alloc((size_t)n * 64 * 4);
  unsigned short* ybfA = (unsigned short*)alloc((size_t)n * 64 * 2);
  unsigned short* ybfB = (unsigned short*)alloc((size_t)n * 64 * 2);
  unsigned short* xlb  = (unsigned short*)alloc((size_t)n * HC * 2);
  float*          xr   = (float*)alloc((size_t)n * HC * 4);
  float4*         sw   = (float4*)alloc((size_t)E * 16);
  int*            srow = (int*)alloc((size_t)E * 4);
  int*            deg  = (int*)alloc((size_t)n * 4);
  int*            offs = (int*)alloc((size_t)(n + 1) * 4);
  int*            cur  = (int*)alloc((size_t)n * 4);
  float*          dis  = (float*)alloc((size_t)n * 4);
  float4*         invq = (float4*)alloc((size_t)n * 16);
  float*          fb   = (float*)alloc((size_t)n * 64 * 4);
  float*          Wext = (float*)alloc((size_t)HC * 64 * 4);
  float*          bb   = (float*)alloc((size_t)HC * 4);

  const double sp = log1p(exp(1.0));  // softplus(1): omega = zeta = Ks
  const float c_decay = (float)(1.0 - 2.0 * sp * sp * 0.01);
  const float c_x     = (float)(-(sp * sp) * 0.01);
  const float c_k     = (float)(sp * 0.01);

  // 1) zero deg
  hipMemsetAsync(deg, 0, (size_t)n * 4, stream);
  // 2) enc + proj + Wext + deg count
  front_kernel<<<1024, 256, 0, stream>>>(x, enc_w, enc_b, dpl_w, dpl_b, dpr_w, dpr_b,
                                         lin_w, lin_b, lo_w, col, Y, X, ybfA, xlb, xr,
                                         Wext, bb, deg, n, E);
  // 3) 1-block scan -> offs/cur/dis
  scan_kernel<<<1, 256, 0, stream>>>(deg, offs, cur, dis, n);
  // 4) counting-sort into CSR
  scatter_kernel<<<(E + 255) / 256, 256, 0, stream>>>(row, col, cur, srow, E);
  // 5) score + layer 1
  score_layer1<<<1024, 256, 0, stream>>>(offs, deg, srow, xlb, xr, att, dis, bb, lo_b,
                                         Wext, ybfA, Y, Y2, ybfB, X, sw, invq, fb,
                                         n, c_decay, c_x, c_k);
  // 6-7) layers 2-3
  layer_fused<<<1024, 256, 0, stream>>>(offs, deg, srow, sw, invq, ybfB, Wext, fb,
                                        Y2, Y, ybfA, X, n, c_decay, c_x, c_k);
  layer_fused<<<1024, 256, 0, stream>>>(offs, deg, srow, sw, invq, ybfA, Wext, fb,
                                        Y, Y2, ybfB, X, n, c_decay, c_x, c_k);
  // 8) layer 4 + decoder
  layer_last_dec<<<1024, 256, 0, stream>>>(offs, deg, srow, sw, invq, ybfB, Wext, fb,
                                           Y2, X, dec_w, dec_b, (float*)d_out,
                                           n, c_decay, c_x, c_k);
}